// Round 1
// baseline (479.512 us; speedup 1.0000x reference)
//
#include <hip/hip_runtime.h>
#include <math.h>

#define Bn 64
#define Rr 36
#define Ww 40
#define Dd 1024
#define EPSf 1e-8f

// ---------------- Gram of masked s: SS[j][w][w'] ----------------
__global__ __launch_bounds__(256) void gram_s_kernel(const float* __restrict__ s,
                                                     const int* __restrict__ s_l,
                                                     float* __restrict__ SS) {
    int j = blockIdx.x;
    int L = s_l[j];
    int t = threadIdx.x;
    __shared__ float tile[Ww][129];
    float acc[7] = {0.f, 0.f, 0.f, 0.f, 0.f, 0.f, 0.f};
    for (int d0 = 0; d0 < Dd; d0 += 128) {
        __syncthreads();
        for (int idx = t; idx < Ww * 128; idx += 256) {
            int w = idx >> 7, dd = idx & 127;
            tile[w][dd] = (w < L) ? s[((size_t)j * Ww + w) * Dd + d0 + dd] : 0.f;
        }
        __syncthreads();
        for (int e = 0; e < 7; ++e) {
            int idx = t + 256 * e;
            if (idx < Ww * Ww) {
                int w1 = idx / Ww, w2 = idx - w1 * Ww;
                float sum = 0.f;
                for (int dd = 0; dd < 128; ++dd) sum += tile[w1][dd] * tile[w2][dd];
                acc[e] += sum;
            }
        }
    }
    for (int e = 0; e < 7; ++e) {
        int idx = t + 256 * e;
        if (idx < Ww * Ww) SS[(size_t)j * Ww * Ww + idx] = acc[e];
    }
}

// ---------------- Gram of im: II[i][r][r'] ----------------
__global__ __launch_bounds__(256) void gram_im_kernel(const float* __restrict__ im,
                                                      float* __restrict__ II) {
    int i = blockIdx.x;
    int t = threadIdx.x;
    __shared__ float tile[Rr][129];
    float acc[6] = {0.f, 0.f, 0.f, 0.f, 0.f, 0.f};
    for (int d0 = 0; d0 < Dd; d0 += 128) {
        __syncthreads();
        for (int idx = t; idx < Rr * 128; idx += 256) {
            int r = idx >> 7, dd = idx & 127;
            tile[r][dd] = im[((size_t)i * Rr + r) * Dd + d0 + dd];
        }
        __syncthreads();
        for (int e = 0; e < 6; ++e) {
            int idx = t + 256 * e;
            if (idx < Rr * Rr) {
                int r1 = idx / Rr, r2 = idx - r1 * Rr;
                float sum = 0.f;
                for (int dd = 0; dd < 128; ++dd) sum += tile[r1][dd] * tile[r2][dd];
                acc[e] += sum;
            }
        }
    }
    for (int e = 0; e < 6; ++e) {
        int idx = t + 256 * e;
        if (idx < Rr * Rr) II[(size_t)i * Rr * Rr + idx] = acc[e];
    }
}

// ---------------- G = im (2304x1024) * s_masked^T (2560x1024)^T ----------------
// 128x128 block tile, BK=16, 256 threads, 8x8 microtile
__global__ __launch_bounds__(256) void gemm_nt_kernel(const float* __restrict__ A,
                                                      const float* __restrict__ Bm,
                                                      const int* __restrict__ s_l,
                                                      float* __restrict__ G) {
    __shared__ float As[16][128];
    __shared__ float Bs[16][128];
    int bn = blockIdx.x;  // N tile (cols, 20)
    int bm = blockIdx.y;  // M tile (rows, 18)
    int t = threadIdx.x;

    int half = t & 1;       // which 8-k chunk
    int lrow = t >> 1;      // 0..127 row within tile
    int mrow = bm * 128 + lrow;
    int nrow = bn * 128 + lrow;
    int jb = nrow / Ww, wb = nrow - jb * Ww;
    bool bvalid = wb < s_l[jb];
    const float* Arow = A + (size_t)mrow * Dd + half * 8;
    const float* Brow = Bm + ((size_t)jb * Ww + wb) * Dd + half * 8;

    int tm = t >> 4, tn = t & 15;  // 16x16 thread grid
    float acc[8][8];
    for (int a = 0; a < 8; ++a)
        for (int b = 0; b < 8; ++b) acc[a][b] = 0.f;

    for (int k0 = 0; k0 < Dd; k0 += 16) {
        float4 a0 = *(const float4*)(Arow + k0);
        float4 a1 = *(const float4*)(Arow + k0 + 4);
        float4 b0 = {0.f, 0.f, 0.f, 0.f}, b1 = {0.f, 0.f, 0.f, 0.f};
        if (bvalid) {
            b0 = *(const float4*)(Brow + k0);
            b1 = *(const float4*)(Brow + k0 + 4);
        }
        __syncthreads();
        float av[8] = {a0.x, a0.y, a0.z, a0.w, a1.x, a1.y, a1.z, a1.w};
        float bv[8] = {b0.x, b0.y, b0.z, b0.w, b1.x, b1.y, b1.z, b1.w};
        for (int u = 0; u < 8; ++u) {
            As[half * 8 + u][lrow] = av[u];
            Bs[half * 8 + u][lrow] = bv[u];
        }
        __syncthreads();
        for (int kk = 0; kk < 16; ++kk) {
            float4 ar0 = *(const float4*)&As[kk][tm * 8];
            float4 ar1 = *(const float4*)&As[kk][tm * 8 + 4];
            float4 br0 = *(const float4*)&Bs[kk][tn * 8];
            float4 br1 = *(const float4*)&Bs[kk][tn * 8 + 4];
            float ar[8] = {ar0.x, ar0.y, ar0.z, ar0.w, ar1.x, ar1.y, ar1.z, ar1.w};
            float br[8] = {br0.x, br0.y, br0.z, br0.w, br1.x, br1.y, br1.z, br1.w};
            for (int mi = 0; mi < 8; ++mi)
                for (int ni = 0; ni < 8; ++ni) acc[mi][ni] += ar[mi] * br[ni];
        }
    }
    // epilogue
    int gcol = bn * 128 + tn * 8;
    for (int mi = 0; mi < 8; ++mi) {
        int grow = bm * 128 + tm * 8 + mi;
        float4 v0 = {acc[mi][0], acc[mi][1], acc[mi][2], acc[mi][3]};
        float4 v1 = {acc[mi][4], acc[mi][5], acc[mi][6], acc[mi][7]};
        *(float4*)(G + (size_t)grow * 2560 + gcol) = v0;
        *(float4*)(G + (size_t)grow * 2560 + gcol + 4) = v1;
    }
}

// ---------------- per-pair kernel: scores + diagonal attn coefficients ----------------
__global__ __launch_bounds__(256) void pair_kernel(const float* __restrict__ G,
                                                   const float* __restrict__ SS,
                                                   const float* __restrict__ II,
                                                   const int* __restrict__ s_l,
                                                   float* __restrict__ scores,
                                                   float* __restrict__ dA,
                                                   float* __restrict__ dB) {
    int j = blockIdx.x, i = blockIdx.y;
    int t = threadIdx.x;
    __shared__ float g[Rr][41];
    __shared__ float aA[Rr][41];   // attn i2t [r][w]
    __shared__ float aB[Ww][37];   // attn t2i [w][r]
    __shared__ float SSs[Ww][41];
    __shared__ float IIs[Rr][37];
    __shared__ float tmp[Ww][41];
    __shared__ float nA[Ww], nB[Rr], s1v[Rr], s2v[Ww];
    __shared__ float sc1, sc2;

    int L = s_l[j];
    for (int idx = t; idx < Rr * Ww; idx += 256) {
        int r = idx / Ww, w = idx - r * Ww;
        g[r][w] = G[(size_t)(i * Rr + r) * 2560 + j * Ww + w];
    }
    for (int idx = t; idx < Ww * Ww; idx += 256)
        SSs[idx / Ww][idx % Ww] = SS[(size_t)j * Ww * Ww + idx];
    for (int idx = t; idx < Rr * Rr; idx += 256)
        IIs[idx / Rr][idx % Rr] = II[(size_t)i * Rr * Rr + idx];
    __syncthreads();

    // norms of leaky(g): nA over regions (per w), nB over words (per r)
    if (t < Ww) {
        float sum = 0.f;
        for (int r = 0; r < Rr; ++r) {
            float x = g[r][t];
            x = x < 0.f ? 0.1f * x : x;
            sum += x * x;
        }
        nA[t] = sqrtf(sum) + EPSf;
    } else if (t >= 64 && t < 64 + Rr) {
        int r = t - 64;
        float sum = 0.f;
        for (int w = 0; w < Ww; ++w) {
            float x = g[r][w];
            x = x < 0.f ? 0.1f * x : x;
            sum += x * x;
        }
        nB[r] = sqrtf(sum) + EPSf;
    }
    __syncthreads();

    // softmaxes
    if (t < Rr) {  // i2t: per region r, softmax over valid words
        int r = t;
        float mx = -1e30f;
        for (int w = 0; w < L; ++w) {
            float x = g[r][w];
            x = x < 0.f ? 0.1f * x : x;
            float lg = 6.f * x / nA[w];
            aA[r][w] = lg;
            if (lg > mx) mx = lg;
        }
        float sum = 0.f;
        for (int w = 0; w < L; ++w) {
            float e = expf(aA[r][w] - mx);
            aA[r][w] = e;
            sum += e;
        }
        float inv = 1.f / sum;
        for (int w = 0; w < L; ++w) aA[r][w] *= inv;
        for (int w = L; w < Ww; ++w) aA[r][w] = 0.f;
    } else if (t >= 64 && t < 64 + Ww) {  // t2i: per word w, softmax over regions
        int w = t - 64;
        float mx = -1e30f;
        for (int r = 0; r < Rr; ++r) {
            float x = g[r][w];
            x = x < 0.f ? 0.1f * x : x;
            float lg = 9.f * x / nB[r];
            aB[w][r] = lg;
            if (lg > mx) mx = lg;
        }
        float sum = 0.f;
        for (int r = 0; r < Rr; ++r) {
            float e = expf(aB[w][r] - mx);
            aB[w][r] = e;
            sum += e;
        }
        float inv = 1.f / sum;
        for (int r = 0; r < Rr; ++r) aB[w][r] *= inv;
    }
    __syncthreads();

    // tmp[r][w'] = sum_w aA[r][w] * SS[w][w']
    for (int idx = t; idx < Rr * Ww; idx += 256) {
        int r = idx / Ww, w2 = idx - r * Ww;
        float sum = 0.f;
        for (int w = 0; w < Ww; ++w) sum += aA[r][w] * SSs[w][w2];
        tmp[r][w2] = sum;
    }
    __syncthreads();
    if (t < Rr) {
        int r = t;
        float dotv = 0.f, q = 0.f;
        for (int w = 0; w < Ww; ++w) {
            dotv += aA[r][w] * g[r][w];
            q += aA[r][w] * tmp[r][w];
        }
        float imn = sqrtf(IIs[r][r]);
        s1v[r] = dotv / fmaxf(imn * sqrtf(fmaxf(q, 0.f)), EPSf);
    }
    __syncthreads();

    // tmp[w][r'] = sum_r aB[w][r] * II[r][r']
    for (int idx = t; idx < Ww * Rr; idx += 256) {
        int w = idx / Rr, r2 = idx - w * Rr;
        float sum = 0.f;
        for (int r = 0; r < Rr; ++r) sum += aB[w][r] * IIs[r][r2];
        tmp[w][r2] = sum;
    }
    __syncthreads();
    if (t < Ww) {
        int w = t;
        float dotv = 0.f, q = 0.f;
        for (int r = 0; r < Rr; ++r) {
            dotv += aB[w][r] * g[r][w];
            q += aB[w][r] * tmp[w][r];
        }
        float sn = sqrtf(SSs[w][w]);
        s2v[w] = dotv / fmaxf(sn * sqrtf(fmaxf(q, 0.f)), EPSf);
    }
    __syncthreads();

    if (t == 0) {
        float sum = 0.f;
        for (int r = 0; r < Rr; ++r) sum += expf(6.f * s1v[r]);
        sc1 = logf(sum) / 6.f;
    } else if (t == 64) {
        float sum = 0.f;
        for (int w = 0; w < L; ++w) sum += expf(6.f * s2v[w]);
        sc2 = logf(sum) / 6.f;
    }
    __syncthreads();
    if (t == 0) scores[i * Bn + j] = 0.5f * (sc1 + sc2);

    if (i == j) {
        if (t < Ww) {
            float sum = 0.f;
            for (int r = 0; r < Rr; ++r) sum += aA[r][t];
            dA[i * Ww + t] = sum * (1.f / (float)Rr);
        } else if (t >= 64 && t < 64 + Rr) {
            int r = t - 64;
            float sum = 0.f;
            for (int w = 0; w < L; ++w) sum += aB[w][r];
            dB[i * Rr + r] = sum / (float)L;
        }
    }
}

// ---------------- diagonal outputs ----------------
__global__ __launch_bounds__(256) void diag_out_kernel(const float* __restrict__ s,
                                                       const float* __restrict__ im,
                                                       const int* __restrict__ s_l,
                                                       const float* __restrict__ dA,
                                                       const float* __restrict__ dB,
                                                       float* __restrict__ out) {
    int i = blockIdx.x;
    int t = threadIdx.x;
    int L = s_l[i];
    __shared__ float aw[Ww], br[Rr];
    if (t < Ww) aw[t] = dA[i * Ww + t];
    if (t >= 64 && t < 64 + Rr) br[t - 64] = dB[i * Rr + (t - 64)];
    __syncthreads();
    for (int d = t; d < Dd; d += 256) {
        float acc1 = 0.f;
        for (int w = 0; w < L; ++w) acc1 += aw[w] * s[((size_t)i * Ww + w) * Dd + d];
        out[1 + (size_t)i * Dd + d] = acc1;
        float acc2 = 0.f;
        for (int r = 0; r < Rr; ++r) acc2 += br[r] * im[((size_t)i * Rr + r) * Dd + d];
        out[1 + (size_t)Bn * Dd + (size_t)i * Dd + d] = acc2;
    }
}

// ---------------- hinge loss over score matrix ----------------
__global__ void loss_kernel(const float* __restrict__ scores, float* __restrict__ out) {
    int t = threadIdx.x;  // 64 threads, one wave
    __shared__ float sc[Bn][Bn + 1];
    for (int idx = t; idx < Bn * Bn; idx += 64) sc[idx >> 6][idx & 63] = scores[idx];
    __syncthreads();
    float dt = sc[t][t];
    float rowmax = 0.f, colmax = 0.f;
    for (int k = 0; k < Bn; ++k) {
        if (k != t) {
            float cs = 0.2f + sc[t][k] - dt;  // cost_s row t (subtract diag[i]=dt)
            if (cs > rowmax) rowmax = cs;
            float ci = 0.2f + sc[k][t] - dt;  // cost_im col t (subtract diag[j]=dt)
            if (ci > colmax) colmax = ci;
        }
    }
    float v = rowmax + colmax;
    for (int off = 32; off; off >>= 1) v += __shfl_down(v, off);
    if (t == 0) out[0] = v;
}

extern "C" void kernel_launch(void* const* d_in, const int* in_sizes, int n_in,
                              void* d_out, int out_size, void* d_ws, size_t ws_size,
                              hipStream_t stream) {
    const float* im = (const float*)d_in[0];
    const float* s = (const float*)d_in[1];
    const int* s_l = (const int*)d_in[2];
    float* out = (float*)d_out;
    float* ws = (float*)d_ws;

    float* G = ws;                               // 2304*2560 = 5,898,240
    float* SS = G + (size_t)2304 * 2560;         // 64*40*40 = 102,400
    float* II = SS + 64 * Ww * Ww;               // 64*36*36 = 82,944
    float* scores = II + 64 * Rr * Rr;           // 4096
    float* dA = scores + 4096;                   // 64*40
    float* dB = dA + Bn * Ww;                    // 64*36

    gram_s_kernel<<<Bn, 256, 0, stream>>>(s, s_l, SS);
    gram_im_kernel<<<Bn, 256, 0, stream>>>(im, II);

    dim3 ggrid(20, 18);
    gemm_nt_kernel<<<ggrid, 256, 0, stream>>>(im, s, s_l, G);

    dim3 pgrid(Bn, Bn);
    pair_kernel<<<pgrid, 256, 0, stream>>>(G, SS, II, s_l, scores, dA, dB);

    diag_out_kernel<<<Bn, 256, 0, stream>>>(s, im, s_l, dA, dB, out);
    loss_kernel<<<1, 64, 0, stream>>>(scores, out);
}

// Round 2
// 346.494 us; speedup vs baseline: 1.3839x; 1.3839x over previous
//
#include <hip/hip_runtime.h>
#include <math.h>

#define Bn 64
#define Rr 36
#define Ww 40
#define Dd 1024
#define GM 2304   // Bn*Rr
#define GN 2560   // Bn*Ww
#define EPSf 1e-8f

typedef unsigned short u16;
typedef __attribute__((ext_vector_type(8))) short bf16x8;
typedef __attribute__((ext_vector_type(4))) float f32x4;

struct alignas(8) U16x4 { u16 x, y, z, w; };

__device__ inline u16 f2bf(float x) {
    unsigned int u = __float_as_uint(x);
    u += 0x7FFFu + ((u >> 16) & 1u);
    return (u16)(u >> 16);
}
__device__ inline float bf2f(u16 h) {
    return __uint_as_float(((unsigned int)h) << 16);
}

// ---------------- fp32 -> bf16 conversion (mask s rows) ----------------
__global__ __launch_bounds__(256) void convert_kernel(const float* __restrict__ im,
                                                      const float* __restrict__ s,
                                                      const int* __restrict__ s_l,
                                                      u16* __restrict__ Ab,
                                                      u16* __restrict__ Bb) {
    const int nA4 = GM * Dd / 4;            // 589824
    const int nB4 = GN * Dd / 4;            // 655360
    int idx = blockIdx.x * 256 + threadIdx.x;
    if (idx < nA4) {
        float4 v = *(const float4*)(im + (size_t)idx * 4);
        U16x4 o = {f2bf(v.x), f2bf(v.y), f2bf(v.z), f2bf(v.w)};
        *(U16x4*)(Ab + (size_t)idx * 4) = o;
    } else if (idx < nA4 + nB4) {
        int i2 = idx - nA4;
        int f = i2 * 4;
        int row = f >> 10;          // 0..2559
        int j = row / Ww, w = row - j * Ww;
        U16x4 o = {0, 0, 0, 0};
        if (w < s_l[j]) {
            float4 v = *(const float4*)(s + (size_t)f);
            o.x = f2bf(v.x); o.y = f2bf(v.y); o.z = f2bf(v.z); o.w = f2bf(v.w);
        }
        *(U16x4*)(Bb + (size_t)i2 * 4) = o;
    }
}

// ---------------- Gram of masked s: SS[j][w][w'] ----------------
__global__ __launch_bounds__(256) void gram_s_kernel(const float* __restrict__ s,
                                                     const int* __restrict__ s_l,
                                                     float* __restrict__ SS) {
    int j = blockIdx.x;
    int L = s_l[j];
    int t = threadIdx.x;
    __shared__ float tile[Ww][129];
    float acc[7] = {0.f, 0.f, 0.f, 0.f, 0.f, 0.f, 0.f};
    for (int d0 = 0; d0 < Dd; d0 += 128) {
        __syncthreads();
        for (int idx = t; idx < Ww * 128; idx += 256) {
            int w = idx >> 7, dd = idx & 127;
            tile[w][dd] = (w < L) ? s[((size_t)j * Ww + w) * Dd + d0 + dd] : 0.f;
        }
        __syncthreads();
        for (int e = 0; e < 7; ++e) {
            int idx = t + 256 * e;
            if (idx < Ww * Ww) {
                int w1 = idx / Ww, w2 = idx - w1 * Ww;
                float sum = 0.f;
                for (int dd = 0; dd < 128; ++dd) sum += tile[w1][dd] * tile[w2][dd];
                acc[e] += sum;
            }
        }
    }
    for (int e = 0; e < 7; ++e) {
        int idx = t + 256 * e;
        if (idx < Ww * Ww) SS[(size_t)j * Ww * Ww + idx] = acc[e];
    }
}

// ---------------- Gram of im: II[i][r][r'] ----------------
__global__ __launch_bounds__(256) void gram_im_kernel(const float* __restrict__ im,
                                                      float* __restrict__ II) {
    int i = blockIdx.x;
    int t = threadIdx.x;
    __shared__ float tile[Rr][129];
    float acc[6] = {0.f, 0.f, 0.f, 0.f, 0.f, 0.f};
    for (int d0 = 0; d0 < Dd; d0 += 128) {
        __syncthreads();
        for (int idx = t; idx < Rr * 128; idx += 256) {
            int r = idx >> 7, dd = idx & 127;
            tile[r][dd] = im[((size_t)i * Rr + r) * Dd + d0 + dd];
        }
        __syncthreads();
        for (int e = 0; e < 6; ++e) {
            int idx = t + 256 * e;
            if (idx < Rr * Rr) {
                int r1 = idx / Rr, r2 = idx - r1 * Rr;
                float sum = 0.f;
                for (int dd = 0; dd < 128; ++dd) sum += tile[r1][dd] * tile[r2][dd];
                acc[e] += sum;
            }
        }
    }
    for (int e = 0; e < 6; ++e) {
        int idx = t + 256 * e;
        if (idx < Rr * Rr) II[(size_t)i * Rr * Rr + idx] = acc[e];
    }
}

// ---------------- MFMA bf16 GEMM: G[m][n] = sum_k Ab[m][k]*Bb[n][k] ----------------
// 128x128 tile, BK=32, 256 threads = 4 waves (2x2), each wave 64x64 = 4x4 frags
template <bool GB>
__global__ __launch_bounds__(256) void gemm_mfma_kernel(const u16* __restrict__ Ab,
                                                        const u16* __restrict__ Bb,
                                                        void* __restrict__ Gv) {
    __shared__ __align__(16) u16 As[128][32];
    __shared__ __align__(16) u16 Bs[128][32];
    int bn = blockIdx.x;   // 20
    int bm = blockIdx.y;   // 18
    int t = threadIdx.x;
    int lane = t & 63, wid = t >> 6;
    int wr = wid >> 1, wc = wid & 1;

    int srow = t >> 2;            // 0..63
    int skofs = (t & 3) * 8;      // ushort offset within row
    const u16* Aptr0 = Ab + (size_t)(bm * 128 + srow) * Dd + skofs;
    const u16* Aptr1 = Ab + (size_t)(bm * 128 + 64 + srow) * Dd + skofs;
    const u16* Bptr0 = Bb + (size_t)(bn * 128 + srow) * Dd + skofs;
    const u16* Bptr1 = Bb + (size_t)(bn * 128 + 64 + srow) * Dd + skofs;

    f32x4 acc[4][4];
    for (int a = 0; a < 4; ++a)
        for (int b = 0; b < 4; ++b) acc[a][b] = (f32x4){0.f, 0.f, 0.f, 0.f};

    int4 ra0 = *(const int4*)Aptr0;
    int4 ra1 = *(const int4*)Aptr1;
    int4 rb0 = *(const int4*)Bptr0;
    int4 rb1 = *(const int4*)Bptr1;

    for (int k0 = 0; k0 < Dd; k0 += 32) {
        __syncthreads();
        *(int4*)&As[srow][skofs] = ra0;
        *(int4*)&As[64 + srow][skofs] = ra1;
        *(int4*)&Bs[srow][skofs] = rb0;
        *(int4*)&Bs[64 + srow][skofs] = rb1;
        __syncthreads();
        if (k0 + 32 < Dd) {
            ra0 = *(const int4*)(Aptr0 + k0 + 32);
            ra1 = *(const int4*)(Aptr1 + k0 + 32);
            rb0 = *(const int4*)(Bptr0 + k0 + 32);
            rb1 = *(const int4*)(Bptr1 + k0 + 32);
        }
        int mrow = wr * 64 + (lane & 15);
        int nrow = wc * 64 + (lane & 15);
        int krd = (lane >> 4) * 8;
        bf16x8 af[4], bf[4];
        for (int mi = 0; mi < 4; ++mi) af[mi] = *(const bf16x8*)&As[mrow + mi * 16][krd];
        for (int ni = 0; ni < 4; ++ni) bf[ni] = *(const bf16x8*)&Bs[nrow + ni * 16][krd];
        for (int mi = 0; mi < 4; ++mi)
            for (int ni = 0; ni < 4; ++ni)
                acc[mi][ni] = __builtin_amdgcn_mfma_f32_16x16x32_bf16(af[mi], bf[ni], acc[mi][ni], 0, 0, 0);
    }

    int crow0 = bm * 128 + wr * 64 + (lane >> 4) * 4;
    int ccol0 = bn * 128 + wc * 64 + (lane & 15);
    for (int mi = 0; mi < 4; ++mi)
        for (int q = 0; q < 4; ++q) {
            int row = crow0 + mi * 16 + q;
            for (int ni = 0; ni < 4; ++ni) {
                float v = acc[mi][ni][q];
                size_t off = (size_t)row * GN + ccol0 + ni * 16;
                if (GB) ((u16*)Gv)[off] = f2bf(v);
                else ((float*)Gv)[off] = v;
            }
        }
}

// ---------------- per-pair kernel ----------------
template <bool GB>
__global__ __launch_bounds__(256) void pair_kernel(const void* __restrict__ Gv,
                                                   const float* __restrict__ SS,
                                                   const float* __restrict__ II,
                                                   const int* __restrict__ s_l,
                                                   float* __restrict__ scores,
                                                   float* __restrict__ dA,
                                                   float* __restrict__ dB) {
    int j = blockIdx.x, i = blockIdx.y;
    int t = threadIdx.x;
    __shared__ float g[Rr][41];
    __shared__ float aA[Rr][41];
    __shared__ float aB[Ww][37];
    __shared__ float SSs[Ww][41];
    __shared__ float IIs[Rr][37];
    __shared__ float tmp[Ww][41];
    __shared__ float invA[Ww], invB[Rr], s1v[Rr], s2v[Ww], red[2];

    int L = s_l[j];

    // ---- loads ----
    if (GB) {
        const u16* Gh = (const u16*)Gv;
        for (int idx = t; idx < Rr * 20; idx += 256) {
            int r = idx / 20, c2 = (idx - (idx / 20) * 20) * 2;
            size_t base = (size_t)(i * Rr + r) * GN + j * Ww + c2;
            unsigned int u = *(const unsigned int*)(Gh + base);
            g[r][c2] = __uint_as_float(u << 16);
            g[r][c2 + 1] = __uint_as_float(u & 0xFFFF0000u);
        }
    } else {
        const float* Gf = (const float*)Gv;
        for (int idx = t; idx < Rr * 10; idx += 256) {
            int r = idx / 10, c4 = (idx - (idx / 10) * 10) * 4;
            float4 v = *(const float4*)(Gf + (size_t)(i * Rr + r) * GN + j * Ww + c4);
            g[r][c4] = v.x; g[r][c4 + 1] = v.y; g[r][c4 + 2] = v.z; g[r][c4 + 3] = v.w;
        }
    }
    for (int idx = t; idx < Ww * 10; idx += 256) {
        int w = idx / 10, c4 = (idx - (idx / 10) * 10) * 4;
        float4 v = *(const float4*)(SS + (size_t)j * Ww * Ww + w * Ww + c4);
        SSs[w][c4] = v.x; SSs[w][c4 + 1] = v.y; SSs[w][c4 + 2] = v.z; SSs[w][c4 + 3] = v.w;
    }
    for (int idx = t; idx < Rr * 9; idx += 256) {
        int r = idx / 9, c4 = (idx - (idx / 9) * 9) * 4;
        float4 v = *(const float4*)(II + (size_t)i * Rr * Rr + r * Rr + c4);
        IIs[r][c4] = v.x; IIs[r][c4 + 1] = v.y; IIs[r][c4 + 2] = v.z; IIs[r][c4 + 3] = v.w;
    }
    __syncthreads();

    // ---- norms -> reciprocal scale ----
    if (t < Ww) {
        float sum = 0.f;
        for (int r = 0; r < Rr; ++r) {
            float x = g[r][t];
            x = x < 0.f ? 0.1f * x : x;
            sum += x * x;
        }
        invA[t] = 6.f / (sqrtf(sum) + EPSf);
    } else if (t >= 64 && t < 64 + Rr) {
        int r = t - 64;
        float sum = 0.f;
        for (int w = 0; w < Ww; ++w) {
            float x = g[r][w];
            x = x < 0.f ? 0.1f * x : x;
            sum += x * x;
        }
        invB[r] = 9.f / (sqrtf(sum) + EPSf);
    }
    __syncthreads();

    // ---- softmaxes ----
    if (t < Rr) {
        int r = t;
        float mx = -1e30f;
        for (int w = 0; w < L; ++w) {
            float x = g[r][w];
            x = x < 0.f ? 0.1f * x : x;
            mx = fmaxf(mx, x * invA[w]);
        }
        float sum = 0.f;
        for (int w = 0; w < L; ++w) {
            float x = g[r][w];
            x = x < 0.f ? 0.1f * x : x;
            float e = __expf(x * invA[w] - mx);
            aA[r][w] = e;
            sum += e;
        }
        float inv = 1.f / sum;
        for (int w = 0; w < L; ++w) aA[r][w] *= inv;
        for (int w = L; w < Ww; ++w) aA[r][w] = 0.f;
    } else if (t >= 64 && t < 64 + Ww) {
        int w = t - 64;
        float mx = -1e30f;
        for (int r = 0; r < Rr; ++r) {
            float x = g[r][w];
            x = x < 0.f ? 0.1f * x : x;
            mx = fmaxf(mx, x * invB[r]);
        }
        float sum = 0.f;
        for (int r = 0; r < Rr; ++r) {
            float x = g[r][w];
            x = x < 0.f ? 0.1f * x : x;
            float e = __expf(x * invB[r] - mx);
            aB[w][r] = e;
            sum += e;
        }
        float inv = 1.f / sum;
        for (int r = 0; r < Rr; ++r) aB[w][r] *= inv;
    }
    __syncthreads();

    // ---- tmp[r][w2] = sum_w aA[r][w] * SS[w][w2] ----
    for (int idx = t; idx < Rr * Ww; idx += 256) {
        int r = idx / Ww, w2 = idx - (idx / Ww) * Ww;
        float sum = 0.f;
        for (int w = 0; w < Ww; ++w) sum += aA[r][w] * SSs[w][w2];
        tmp[r][w2] = sum;
    }
    __syncthreads();
    if (t < Rr) {
        int r = t;
        float dot = 0.f, q = 0.f;
        for (int w = 0; w < Ww; ++w) {
            float a = aA[r][w];
            dot += a * g[r][w];
            q += a * tmp[r][w];
        }
        s1v[r] = dot / fmaxf(sqrtf(IIs[r][r]) * sqrtf(fmaxf(q, 0.f)), EPSf);
    }
    __syncthreads();

    // ---- tmp[w][r2] = sum_r aB[w][r] * II[r][r2] ----
    for (int idx = t; idx < Ww * Rr; idx += 256) {
        int w = idx / Rr, r2 = idx - (idx / Rr) * Rr;
        float sum = 0.f;
        for (int r = 0; r < Rr; ++r) sum += aB[w][r] * IIs[r][r2];
        tmp[w][r2] = sum;
    }
    __syncthreads();
    if (t < Ww) {
        int w = t;
        float dot = 0.f, q = 0.f;
        for (int r = 0; r < Rr; ++r) {
            float a = aB[w][r];
            dot += a * g[r][w];
            q += a * tmp[w][r];
        }
        s2v[w] = dot / fmaxf(sqrtf(SSs[w][w]) * sqrtf(fmaxf(q, 0.f)), EPSf);
    }
    __syncthreads();

    if (t == 0) {
        float sum = 0.f;
        for (int r = 0; r < Rr; ++r) sum += __expf(6.f * s1v[r]);
        red[0] = __logf(sum) * (1.f / 6.f);
    } else if (t == 64) {
        float sum = 0.f;
        for (int w = 0; w < L; ++w) sum += __expf(6.f * s2v[w]);
        red[1] = __logf(sum) * (1.f / 6.f);
    }
    __syncthreads();
    if (t == 0) scores[i * Bn + j] = 0.5f * (red[0] + red[1]);

    if (i == j) {
        if (t < Ww) {
            float sum = 0.f;
            for (int r = 0; r < Rr; ++r) sum += aA[r][t];
            dA[i * Ww + t] = sum * (1.f / (float)Rr);
        } else if (t >= 64 && t < 64 + Rr) {
            int r = t - 64;
            float sum = 0.f;
            for (int w = 0; w < L; ++w) sum += aB[w][r];
            dB[i * Rr + r] = sum / (float)L;
        }
    }
}

// ---------------- diagonal outputs ----------------
__global__ __launch_bounds__(256) void diag_out_kernel(const float* __restrict__ s,
                                                       const float* __restrict__ im,
                                                       const int* __restrict__ s_l,
                                                       const float* __restrict__ dA,
                                                       const float* __restrict__ dB,
                                                       float* __restrict__ out) {
    int i = blockIdx.x;
    int t = threadIdx.x;
    int L = s_l[i];
    __shared__ float aw[Ww], br[Rr];
    if (t < Ww) aw[t] = dA[i * Ww + t];
    if (t >= 64 && t < 64 + Rr) br[t - 64] = dB[i * Rr + (t - 64)];
    __syncthreads();
    for (int d = t; d < Dd; d += 256) {
        float acc1 = 0.f;
        for (int w = 0; w < L; ++w) acc1 += aw[w] * s[((size_t)i * Ww + w) * Dd + d];
        out[1 + (size_t)i * Dd + d] = acc1;
        float acc2 = 0.f;
        for (int r = 0; r < Rr; ++r) acc2 += br[r] * im[((size_t)i * Rr + r) * Dd + d];
        out[1 + (size_t)Bn * Dd + (size_t)i * Dd + d] = acc2;
    }
}

// ---------------- hinge loss ----------------
__global__ void loss_kernel(const float* __restrict__ scores, float* __restrict__ out) {
    int t = threadIdx.x;
    __shared__ float sc[Bn][Bn + 1];
    for (int idx = t; idx < Bn * Bn; idx += 64) sc[idx >> 6][idx & 63] = scores[idx];
    __syncthreads();
    float dt = sc[t][t];
    float rowmax = 0.f, colmax = 0.f;
    for (int k = 0; k < Bn; ++k) {
        if (k != t) {
            float cs = 0.2f + sc[t][k] - dt;
            if (cs > rowmax) rowmax = cs;
            float ci = 0.2f + sc[k][t] - dt;
            if (ci > colmax) colmax = ci;
        }
    }
    float v = rowmax + colmax;
    for (int off = 32; off; off >>= 1) v += __shfl_down(v, off);
    if (t == 0) out[0] = v;
}

extern "C" void kernel_launch(void* const* d_in, const int* in_sizes, int n_in,
                              void* d_out, int out_size, void* d_ws, size_t ws_size,
                              hipStream_t stream) {
    const float* im = (const float*)d_in[0];
    const float* s = (const float*)d_in[1];
    const int* s_l = (const int*)d_in[2];
    float* out = (float*)d_out;

    const size_t nAb = (size_t)GM * Dd;   // 2359296 u16
    const size_t nBb = (size_t)GN * Dd;   // 2621440 u16
    u16* Ab = (u16*)d_ws;
    u16* Bb = Ab + nAb;
    float* SS = (float*)(Bb + nBb);
    float* II = SS + (size_t)Bn * Ww * Ww;
    float* scores = II + (size_t)Bn * Rr * Rr;
    float* dA = scores + Bn * Bn;
    float* dB = dA + Bn * Ww;
    void* G = (void*)(dB + Bn * Rr);
    size_t base_bytes = (char*)G - (char*)d_ws;
    bool g_fp32 = (ws_size >= base_bytes + (size_t)GM * GN * 4);

    int nconv = (GM * Dd + GN * Dd) / 4;
    convert_kernel<<<(nconv + 255) / 256, 256, 0, stream>>>(im, s, s_l, Ab, Bb);
    gram_s_kernel<<<Bn, 256, 0, stream>>>(s, s_l, SS);
    gram_im_kernel<<<Bn, 256, 0, stream>>>(im, II);

    dim3 ggrid(GN / 128, GM / 128);
    dim3 pgrid(Bn, Bn);
    if (g_fp32) {
        gemm_mfma_kernel<false><<<ggrid, 256, 0, stream>>>(Ab, Bb, G);
        pair_kernel<false><<<pgrid, 256, 0, stream>>>(G, SS, II, s_l, scores, dA, dB);
    } else {
        gemm_mfma_kernel<true><<<ggrid, 256, 0, stream>>>(Ab, Bb, G);
        pair_kernel<true><<<pgrid, 256, 0, stream>>>(G, SS, II, s_l, scores, dA, dB);
    }

    diag_out_kernel<<<Bn, 256, 0, stream>>>(s, im, s_l, dA, dB, out);
    loss_kernel<<<1, 64, 0, stream>>>(scores, out);
}

// Round 3
// 139.469 us; speedup vs baseline: 3.4381x; 2.4844x over previous
//
#include <hip/hip_runtime.h>
#include <math.h>

#define Bn 64
#define Rr 36
#define Ww 40
#define Dd 1024
#define GM 2304   // Bn*Rr
#define GN 2560   // Bn*Ww
#define EPSf 1e-8f

typedef unsigned short u16;
typedef __attribute__((ext_vector_type(8))) short bf16x8;
typedef __attribute__((ext_vector_type(4))) float f32x4;

struct alignas(8) U16x4 { u16 x, y, z, w; };

__device__ inline u16 f2bf(float x) {
    unsigned int u = __float_as_uint(x);
    u += 0x7FFFu + ((u >> 16) & 1u);
    return (u16)(u >> 16);
}

// ---------------- fp32 -> bf16 conversion (mask s rows) ----------------
__global__ __launch_bounds__(256) void convert_kernel(const float* __restrict__ im,
                                                      const float* __restrict__ s,
                                                      const int* __restrict__ s_l,
                                                      u16* __restrict__ Ab,
                                                      u16* __restrict__ Bb) {
    const int nA4 = GM * Dd / 4;
    const int nB4 = GN * Dd / 4;
    int idx = blockIdx.x * 256 + threadIdx.x;
    if (idx < nA4) {
        float4 v = *(const float4*)(im + (size_t)idx * 4);
        U16x4 o = {f2bf(v.x), f2bf(v.y), f2bf(v.z), f2bf(v.w)};
        *(U16x4*)(Ab + (size_t)idx * 4) = o;
    } else if (idx < nA4 + nB4) {
        int i2 = idx - nA4;
        int f = i2 * 4;
        int row = f >> 10;
        int j = row / Ww, w = row - j * Ww;
        U16x4 o = {0, 0, 0, 0};
        if (w < s_l[j]) {
            float4 v = *(const float4*)(s + (size_t)f);
            o.x = f2bf(v.x); o.y = f2bf(v.y); o.z = f2bf(v.z); o.w = f2bf(v.w);
        }
        *(U16x4*)(Bb + (size_t)i2 * 4) = o;
    }
}

// ---------------- Grams via single-wave MFMA (SS = Bj@Bj^T, II = Ai@Ai^T) ----------------
// 128 blocks of 64 threads. Symmetric source => A-frag == B-frag registers.
// OOB rows (>=n, up to 47) read in-bounds-of-ws garbage; they only affect
// output slots with row>=n or col>=n which are never stored.
__global__ __launch_bounds__(64) void gram_mfma_kernel(const u16* __restrict__ Ab,
                                                       const u16* __restrict__ Bb,
                                                       float* __restrict__ SS,
                                                       float* __restrict__ II) {
    int b = blockIdx.x;
    bool isS = b < Bn;
    int idx = isS ? b : b - Bn;
    int n = isS ? Ww : Rr;
    const u16* base = isS ? (Bb + (size_t)idx * Ww * Dd) : (Ab + (size_t)idx * Rr * Dd);
    float* outp = isS ? (SS + (size_t)idx * Ww * Ww) : (II + (size_t)idx * Rr * Rr);
    int lane = threadIdx.x;
    int frow = lane & 15;
    int fk = (lane >> 4) * 8;

    f32x4 acc[3][3];
    for (int m = 0; m < 3; ++m)
        for (int p = 0; p < 3; ++p) acc[m][p] = (f32x4){0.f, 0.f, 0.f, 0.f};

    for (int k0 = 0; k0 < Dd; k0 += 32) {
        bf16x8 f[3];
        for (int m = 0; m < 3; ++m)
            f[m] = *(const bf16x8*)(base + (size_t)(m * 16 + frow) * Dd + k0 + fk);
        for (int m = 0; m < 3; ++m)
            for (int p = 0; p < 3; ++p)
                acc[m][p] = __builtin_amdgcn_mfma_f32_16x16x32_bf16(f[m], f[p], acc[m][p], 0, 0, 0);
    }
    int crow = (lane >> 4) * 4;
    int ccol = lane & 15;
    for (int m = 0; m < 3; ++m)
        for (int p = 0; p < 3; ++p)
            for (int q = 0; q < 4; ++q) {
                int row = m * 16 + crow + q;
                int col = p * 16 + ccol;
                if (row < n && col < n) outp[row * n + col] = acc[m][p][q];
            }
}

// ---------------- MFMA bf16 GEMM: G[m][n] = sum_k Ab[m][k]*Bb[n][k] ----------------
template <bool GB>
__global__ __launch_bounds__(256) void gemm_mfma_kernel(const u16* __restrict__ Ab,
                                                        const u16* __restrict__ Bb,
                                                        void* __restrict__ Gv) {
    __shared__ __align__(16) u16 As[128][32];
    __shared__ __align__(16) u16 Bs[128][32];
    int bn = blockIdx.x;
    int bm = blockIdx.y;
    int t = threadIdx.x;
    int lane = t & 63, wid = t >> 6;
    int wr = wid >> 1, wc = wid & 1;

    int srow = t >> 2;
    int skofs = (t & 3) * 8;
    const u16* Aptr0 = Ab + (size_t)(bm * 128 + srow) * Dd + skofs;
    const u16* Aptr1 = Ab + (size_t)(bm * 128 + 64 + srow) * Dd + skofs;
    const u16* Bptr0 = Bb + (size_t)(bn * 128 + srow) * Dd + skofs;
    const u16* Bptr1 = Bb + (size_t)(bn * 128 + 64 + srow) * Dd + skofs;

    f32x4 acc[4][4];
    for (int a = 0; a < 4; ++a)
        for (int b = 0; b < 4; ++b) acc[a][b] = (f32x4){0.f, 0.f, 0.f, 0.f};

    int4 ra0 = *(const int4*)Aptr0;
    int4 ra1 = *(const int4*)Aptr1;
    int4 rb0 = *(const int4*)Bptr0;
    int4 rb1 = *(const int4*)Bptr1;

    for (int k0 = 0; k0 < Dd; k0 += 32) {
        __syncthreads();
        *(int4*)&As[srow][skofs] = ra0;
        *(int4*)&As[64 + srow][skofs] = ra1;
        *(int4*)&Bs[srow][skofs] = rb0;
        *(int4*)&Bs[64 + srow][skofs] = rb1;
        __syncthreads();
        if (k0 + 32 < Dd) {
            ra0 = *(const int4*)(Aptr0 + k0 + 32);
            ra1 = *(const int4*)(Aptr1 + k0 + 32);
            rb0 = *(const int4*)(Bptr0 + k0 + 32);
            rb1 = *(const int4*)(Bptr1 + k0 + 32);
        }
        int mrow = wr * 64 + (lane & 15);
        int nrow = wc * 64 + (lane & 15);
        int krd = (lane >> 4) * 8;
        bf16x8 af[4], bf[4];
        for (int mi = 0; mi < 4; ++mi) af[mi] = *(const bf16x8*)&As[mrow + mi * 16][krd];
        for (int ni = 0; ni < 4; ++ni) bf[ni] = *(const bf16x8*)&Bs[nrow + ni * 16][krd];
        for (int mi = 0; mi < 4; ++mi)
            for (int ni = 0; ni < 4; ++ni)
                acc[mi][ni] = __builtin_amdgcn_mfma_f32_16x16x32_bf16(af[mi], bf[ni], acc[mi][ni], 0, 0, 0);
    }

    int crow0 = bm * 128 + wr * 64 + (lane >> 4) * 4;
    int ccol0 = bn * 128 + wc * 64 + (lane & 15);
    for (int mi = 0; mi < 4; ++mi)
        for (int q = 0; q < 4; ++q) {
            int row = crow0 + mi * 16 + q;
            for (int ni = 0; ni < 4; ++ni) {
                float v = acc[mi][ni][q];
                size_t off = (size_t)row * GN + ccol0 + ni * 16;
                if (GB) ((u16*)Gv)[off] = f2bf(v);
                else ((float*)Gv)[off] = v;
            }
        }
}

// ---------------- per-pair kernel (register-tiled, transposed attn storage) ----------------
template <bool GB>
__global__ __launch_bounds__(256) void pair_kernel(const void* __restrict__ Gv,
                                                   const float* __restrict__ SS,
                                                   const float* __restrict__ II,
                                                   const int* __restrict__ s_l,
                                                   float* __restrict__ scores,
                                                   float* __restrict__ dA,
                                                   float* __restrict__ dB) {
    int j = blockIdx.x, i = blockIdx.y;
    int t = threadIdx.x;
    __shared__ float g[Rr][44];
    __shared__ float aAT[Ww][Ww];   // aAT[w][r] = attn_i2t[r][w]
    __shared__ float aBT[Rr][Ww];   // aBT[r][w] = attn_t2i[w][r]
    __shared__ float SSs[Ww][Ww];
    __shared__ float IIs[Rr][Ww];
    __shared__ float qpA[9][4][12];
    __shared__ float qpB[10][4][12];
    __shared__ float invA[Ww], invB[Rr], s1v[Rr], s2v[Ww], red[2];

    int L = s_l[j];

    // ---- loads ----
    if (GB) {
        const u16* Gh = (const u16*)Gv;
        for (int idx = t; idx < Rr * 20; idx += 256) {
            int r = idx / 20, c2 = (idx - (idx / 20) * 20) * 2;
            unsigned int u = *(const unsigned int*)(Gh + (size_t)(i * Rr + r) * GN + j * Ww + c2);
            g[r][c2] = __uint_as_float(u << 16);
            g[r][c2 + 1] = __uint_as_float(u & 0xFFFF0000u);
        }
    } else {
        const float* Gf = (const float*)Gv;
        for (int idx = t; idx < Rr * 10; idx += 256) {
            int r = idx / 10, c4 = (idx - (idx / 10) * 10) * 4;
            float4 v = *(const float4*)(Gf + (size_t)(i * Rr + r) * GN + j * Ww + c4);
            *(float4*)&g[r][c4] = v;
        }
    }
    for (int idx = t; idx < Ww * 10; idx += 256) {
        int w = idx / 10, c4 = (idx - (idx / 10) * 10) * 4;
        *(float4*)&SSs[w][c4] = *(const float4*)(SS + (size_t)j * Ww * Ww + w * Ww + c4);
    }
    for (int idx = t; idx < Rr * 9; idx += 256) {
        int r = idx / 9, c4 = (idx - (idx / 9) * 9) * 4;
        *(float4*)&IIs[r][c4] = *(const float4*)(II + (size_t)i * Rr * Rr + r * Rr + c4);
    }
    __syncthreads();

    // ---- norms -> reciprocal scale ----
    if (t < Ww) {
        float sum = 0.f;
        for (int r = 0; r < Rr; ++r) {
            float x = g[r][t];
            x = x < 0.f ? 0.1f * x : x;
            sum += x * x;
        }
        invA[t] = 6.f / (sqrtf(sum) + EPSf);
    } else if (t >= 64 && t < 64 + Rr) {
        int r = t - 64;
        float sum = 0.f;
        for (int q4 = 0; q4 < 10; ++q4) {
            float4 v = *(const float4*)&g[r][q4 * 4];
            float x0 = v.x < 0.f ? 0.1f * v.x : v.x;
            float x1 = v.y < 0.f ? 0.1f * v.y : v.y;
            float x2 = v.z < 0.f ? 0.1f * v.z : v.z;
            float x3 = v.w < 0.f ? 0.1f * v.w : v.w;
            sum += x0 * x0 + x1 * x1 + x2 * x2 + x3 * x3;
        }
        invB[r] = 9.f / (sqrtf(sum) + EPSf);
    }
    __syncthreads();

    // ---- softmaxes (write transposed) ----
    if (t < Rr) {
        int r = t;
        float mx = -1e30f;
        for (int w = 0; w < L; ++w) {
            float x = g[r][w];
            x = x < 0.f ? 0.1f * x : x;
            mx = fmaxf(mx, x * invA[w]);
        }
        float sum = 0.f;
        for (int w = 0; w < L; ++w) {
            float x = g[r][w];
            x = x < 0.f ? 0.1f * x : x;
            float e = __expf(x * invA[w] - mx);
            aAT[w][r] = e;
            sum += e;
        }
        float inv = 1.f / sum;
        for (int w = 0; w < L; ++w) aAT[w][r] *= inv;
        for (int w = L; w < Ww; ++w) aAT[w][r] = 0.f;
    } else if (t >= 64 && t < 64 + Ww) {
        int w = t - 64;
        float mx = -1e30f;
        for (int r = 0; r < Rr; ++r) {
            float x = g[r][w];
            x = x < 0.f ? 0.1f * x : x;
            mx = fmaxf(mx, x * invB[r]);
        }
        float sum = 0.f;
        for (int r = 0; r < Rr; ++r) {
            float x = g[r][w];
            x = x < 0.f ? 0.1f * x : x;
            float e = __expf(x * invB[r] - mx);
            aBT[r][w] = e;
            sum += e;
        }
        float inv = 1.f / sum;
        for (int r = 0; r < Rr; ++r) aBT[r][w] *= inv;
    }
    __syncthreads();

    // ---- register-tiled quadratic forms: q = a^T M a (fused, no tmp arrays) ----
    if (t < 90) {
        int rg = t / 10, wg = t - (t / 10) * 10;
        float a[4][4];
        for (int x = 0; x < 4; ++x)
            for (int y = 0; y < 4; ++y) a[x][y] = 0.f;
        for (int w = 0; w < Ww; ++w) {
            float4 av = *(const float4*)&aAT[w][rg * 4];
            float4 sv = *(const float4*)&SSs[w][wg * 4];
            float avf[4] = {av.x, av.y, av.z, av.w};
            float svf[4] = {sv.x, sv.y, sv.z, sv.w};
            for (int ri = 0; ri < 4; ++ri)
                for (int wj = 0; wj < 4; ++wj) a[ri][wj] += avf[ri] * svf[wj];
        }
        float qp[4] = {0.f, 0.f, 0.f, 0.f};
        for (int wj = 0; wj < 4; ++wj) {
            float4 av2 = *(const float4*)&aAT[wg * 4 + wj][rg * 4];
            float avf[4] = {av2.x, av2.y, av2.z, av2.w};
            for (int ri = 0; ri < 4; ++ri) qp[ri] += avf[ri] * a[ri][wj];
        }
        for (int ri = 0; ri < 4; ++ri) qpA[rg][ri][wg] = qp[ri];
    } else if (t >= 128 && t < 218) {
        int u = t - 128;
        int wg = u / 9, rg = u - (u / 9) * 9;
        float a[4][4];
        for (int x = 0; x < 4; ++x)
            for (int y = 0; y < 4; ++y) a[x][y] = 0.f;
        for (int r = 0; r < Rr; ++r) {
            float4 bv = *(const float4*)&aBT[r][wg * 4];
            float4 iv = *(const float4*)&IIs[r][rg * 4];
            float bvf[4] = {bv.x, bv.y, bv.z, bv.w};
            float ivf[4] = {iv.x, iv.y, iv.z, iv.w};
            for (int wi = 0; wi < 4; ++wi)
                for (int rj = 0; rj < 4; ++rj) a[wi][rj] += bvf[wi] * ivf[rj];
        }
        float qp[4] = {0.f, 0.f, 0.f, 0.f};
        for (int rj = 0; rj < 4; ++rj) {
            float4 bv2 = *(const float4*)&aBT[rg * 4 + rj][wg * 4];
            float bvf[4] = {bv2.x, bv2.y, bv2.z, bv2.w};
            for (int wi = 0; wi < 4; ++wi) qp[wi] += bvf[wi] * a[wi][rj];
        }
        for (int wi = 0; wi < 4; ++wi) qpB[wg][wi][rg] = qp[wi];
    }
    __syncthreads();

    // ---- dots + sims (2 lanes per row/col); diag outputs concurrent ----
    if (t < 72) {
        int r = t >> 1, half = t & 1;
        float dot = 0.f;
        for (int w = half * 20; w < half * 20 + 20; ++w) dot += aAT[w][r] * g[r][w];
        dot += __shfl_xor(dot, 1);
        if (!half) {
            float q = 0.f;
            for (int wg = 0; wg < 10; ++wg) q += qpA[r >> 2][r & 3][wg];
            s1v[r] = dot / fmaxf(sqrtf(IIs[r][r]) * sqrtf(fmaxf(q, 0.f)), EPSf);
        }
    } else if (t >= 128 && t < 208) {
        int u = t - 128;
        int w = u >> 1, half = u & 1;
        float dot = 0.f;
        for (int r = half * 18; r < half * 18 + 18; ++r) dot += aBT[r][w] * g[r][w];
        dot += __shfl_xor(dot, 1);
        if (!half) {
            float q = 0.f;
            for (int rg = 0; rg < 9; ++rg) q += qpB[w >> 2][w & 3][rg];
            s2v[w] = dot / fmaxf(sqrtf(SSs[w][w]) * sqrtf(fmaxf(q, 0.f)), EPSf);
        }
    }
    if (i == j) {
        if (t >= 216) {
            int w = t - 216;
            float sum = 0.f;
            for (int r = 0; r < Rr; ++r) sum += aAT[w][r];
            dA[i * Ww + w] = sum * (1.f / (float)Rr);
        } else if (t >= 90 && t < 90 + Rr) {
            int r = t - 90;
            float sum = 0.f;
            for (int w = 0; w < L; ++w) sum += aBT[r][w];
            dB[i * Rr + r] = sum / (float)L;
        }
    }
    __syncthreads();

    // ---- LSE reductions (wave-parallel) ----
    if (t < 64) {
        float e = (t < Rr) ? __expf(6.f * s1v[t]) : 0.f;
        for (int off = 32; off; off >>= 1) e += __shfl_down(e, off);
        if (t == 0) red[0] = __logf(e) * (1.f / 6.f);
    } else if (t < 128) {
        int x = t - 64;
        float e = (x < L) ? __expf(6.f * s2v[x]) : 0.f;
        for (int off = 32; off; off >>= 1) e += __shfl_down(e, off);
        if (x == 0) red[1] = __logf(e) * (1.f / 6.f);
    }
    __syncthreads();
    if (t == 0) scores[i * Bn + j] = 0.5f * (red[0] + red[1]);
}

// ---------------- diagonal outputs ----------------
__global__ __launch_bounds__(256) void diag_out_kernel(const float* __restrict__ s,
                                                       const float* __restrict__ im,
                                                       const int* __restrict__ s_l,
                                                       const float* __restrict__ dA,
                                                       const float* __restrict__ dB,
                                                       float* __restrict__ out) {
    int i = blockIdx.x;
    int d = blockIdx.y * 256 + threadIdx.x;
    int t = threadIdx.x;
    int L = s_l[i];
    __shared__ float aw[Ww], br[Rr];
    if (t < Ww) aw[t] = dA[i * Ww + t];
    if (t >= 64 && t < 64 + Rr) br[t - 64] = dB[i * Rr + (t - 64)];
    __syncthreads();
    float acc1 = 0.f;
    for (int w = 0; w < L; ++w) acc1 += aw[w] * s[((size_t)i * Ww + w) * Dd + d];
    out[1 + (size_t)i * Dd + d] = acc1;
    float acc2 = 0.f;
    for (int r = 0; r < Rr; ++r) acc2 += br[r] * im[((size_t)i * Rr + r) * Dd + d];
    out[1 + (size_t)Bn * Dd + (size_t)i * Dd + d] = acc2;
}

// ---------------- hinge loss ----------------
__global__ void loss_kernel(const float* __restrict__ scores, float* __restrict__ out) {
    int t = threadIdx.x;
    __shared__ float sc[Bn][Bn + 1];
    for (int idx = t; idx < Bn * Bn; idx += 64) sc[idx >> 6][idx & 63] = scores[idx];
    __syncthreads();
    float dt = sc[t][t];
    float rowmax = 0.f, colmax = 0.f;
    for (int k = 0; k < Bn; ++k) {
        if (k != t) {
            float cs = 0.2f + sc[t][k] - dt;
            if (cs > rowmax) rowmax = cs;
            float ci = 0.2f + sc[k][t] - dt;
            if (ci > colmax) colmax = ci;
        }
    }
    float v = rowmax + colmax;
    for (int off = 32; off; off >>= 1) v += __shfl_down(v, off);
    if (t == 0) out[0] = v;
}

extern "C" void kernel_launch(void* const* d_in, const int* in_sizes, int n_in,
                              void* d_out, int out_size, void* d_ws, size_t ws_size,
                              hipStream_t stream) {
    const float* im = (const float*)d_in[0];
    const float* s = (const float*)d_in[1];
    const int* s_l = (const int*)d_in[2];
    float* out = (float*)d_out;

    const size_t nAb = (size_t)GM * Dd;
    const size_t nBb = (size_t)GN * Dd;
    u16* Ab = (u16*)d_ws;
    u16* Bb = Ab + nAb;
    float* SS = (float*)(Bb + nBb);
    float* II = SS + (size_t)Bn * Ww * Ww;
    float* scores = II + (size_t)Bn * Rr * Rr;
    float* dA = scores + Bn * Bn;
    float* dB = dA + Bn * Ww;
    void* G = (void*)(dB + Bn * Rr);
    size_t base_bytes = (char*)G - (char*)d_ws;
    bool g_fp32 = (ws_size >= base_bytes + (size_t)GM * GN * 4);

    int nconv = (GM * Dd + GN * Dd) / 4;
    convert_kernel<<<(nconv + 255) / 256, 256, 0, stream>>>(im, s, s_l, Ab, Bb);
    gram_mfma_kernel<<<2 * Bn, 64, 0, stream>>>(Ab, Bb, SS, II);

    dim3 ggrid(GN / 128, GM / 128);
    dim3 pgrid(Bn, Bn);
    if (g_fp32) {
        gemm_mfma_kernel<false><<<ggrid, 256, 0, stream>>>(Ab, Bb, G);
        pair_kernel<false><<<pgrid, 256, 0, stream>>>(G, SS, II, s_l, scores, dA, dB);
    } else {
        gemm_mfma_kernel<true><<<ggrid, 256, 0, stream>>>(Ab, Bb, G);
        pair_kernel<true><<<pgrid, 256, 0, stream>>>(G, SS, II, s_l, scores, dA, dB);
    }

    dim3 dgrid(Bn, 4);
    diag_out_kernel<<<dgrid, 256, 0, stream>>>(s, im, s_l, dA, dB, out);
    loss_kernel<<<1, 64, 0, stream>>>(scores, out);
}

// Round 4
// 119.287 us; speedup vs baseline: 4.0198x; 1.1692x over previous
//
#include <hip/hip_runtime.h>
#include <math.h>

#define Bn 64
#define Rr 36
#define Ww 40
#define Dd 1024
#define GM 2304   // Bn*Rr
#define GN 2560   // Bn*Ww
#define EPSf 1e-8f

typedef unsigned short u16;
typedef __attribute__((ext_vector_type(8))) short bf16x8;
typedef __attribute__((ext_vector_type(4))) float f32x4;

struct alignas(8) U16x4 { u16 x, y, z, w; };

__device__ inline u16 f2bf(float x) {
    unsigned int u = __float_as_uint(x);
    u += 0x7FFFu + ((u >> 16) & 1u);
    return (u16)(u >> 16);
}

__device__ __forceinline__ void gl_lds16(const u16* g, u16* l) {
    __builtin_amdgcn_global_load_lds(
        (const __attribute__((address_space(1))) void*)g,
        (__attribute__((address_space(3))) void*)l, 16, 0, 0);
}

// ---------------- fp32 -> bf16 conversion (mask s rows) ----------------
__global__ __launch_bounds__(256) void convert_kernel(const float* __restrict__ im,
                                                      const float* __restrict__ s,
                                                      const int* __restrict__ s_l,
                                                      u16* __restrict__ Ab,
                                                      u16* __restrict__ Bb) {
    const int nA4 = GM * Dd / 4;
    const int nB4 = GN * Dd / 4;
    int idx = blockIdx.x * 256 + threadIdx.x;
    if (idx < nA4) {
        float4 v = *(const float4*)(im + (size_t)idx * 4);
        U16x4 o = {f2bf(v.x), f2bf(v.y), f2bf(v.z), f2bf(v.w)};
        *(U16x4*)(Ab + (size_t)idx * 4) = o;
    } else if (idx < nA4 + nB4) {
        int i2 = idx - nA4;
        int f = i2 * 4;
        int row = f >> 10;
        int j = row / Ww, w = row - j * Ww;
        U16x4 o = {0, 0, 0, 0};
        if (w < s_l[j]) {
            float4 v = *(const float4*)(s + (size_t)f);
            o.x = f2bf(v.x); o.y = f2bf(v.y); o.z = f2bf(v.z); o.w = f2bf(v.w);
        }
        *(U16x4*)(Bb + (size_t)i2 * 4) = o;
    }
}

// ---------------- Grams via single-wave MFMA ----------------
// OOB rows (>=n, up to 47) read adjacent ws data; affected output slots are
// guarded (row<n && col<n) and never stored.
__global__ __launch_bounds__(64) void gram_mfma_kernel(const u16* __restrict__ Ab,
                                                       const u16* __restrict__ Bb,
                                                       float* __restrict__ SS,
                                                       float* __restrict__ II) {
    int b = blockIdx.x;
    bool isS = b < Bn;
    int idx = isS ? b : b - Bn;
    int n = isS ? Ww : Rr;
    const u16* base = isS ? (Bb + (size_t)idx * Ww * Dd) : (Ab + (size_t)idx * Rr * Dd);
    float* outp = isS ? (SS + (size_t)idx * Ww * Ww) : (II + (size_t)idx * Rr * Rr);
    int lane = threadIdx.x;
    int frow = lane & 15;
    int fk = (lane >> 4) * 8;

    f32x4 acc[3][3];
    for (int m = 0; m < 3; ++m)
        for (int p = 0; p < 3; ++p) acc[m][p] = (f32x4){0.f, 0.f, 0.f, 0.f};

    for (int k0 = 0; k0 < Dd; k0 += 32) {
        bf16x8 f[3];
        for (int m = 0; m < 3; ++m)
            f[m] = *(const bf16x8*)(base + (size_t)(m * 16 + frow) * Dd + k0 + fk);
        for (int m = 0; m < 3; ++m)
            for (int p = 0; p < 3; ++p)
                acc[m][p] = __builtin_amdgcn_mfma_f32_16x16x32_bf16(f[m], f[p], acc[m][p], 0, 0, 0);
    }
    int crow = (lane >> 4) * 4;
    int ccol = lane & 15;
    for (int m = 0; m < 3; ++m)
        for (int p = 0; p < 3; ++p)
            for (int q = 0; q < 4; ++q) {
                int row = m * 16 + crow + q;
                int col = p * 16 + ccol;
                if (row < n && col < n) outp[row * n + col] = acc[m][p][q];
            }
}

// ---------------- MFMA bf16 GEMM with global_load_lds staging ----------------
// 64x128 tile, BK=32, 256 threads = 4 waves (2x2), wave tile 32x64 (2x4 frags)
// grid (GN/128=20, GM/64=36) = 720 blocks
template <bool GB>
__global__ __launch_bounds__(256) void gemm_mfma_kernel(const u16* __restrict__ Ab,
                                                        const u16* __restrict__ Bb,
                                                        void* __restrict__ Gv) {
    __shared__ __align__(16) u16 As[64][32];
    __shared__ __align__(16) u16 Bs[128][32];
    int bn = blockIdx.x;
    int bm = blockIdx.y;
    int t = threadIdx.x;
    int lane = t & 63, wid = t >> 6;
    int wr = wid >> 1, wc = wid & 1;

    // staging: wave w covers 16 rows (64 lanes x 16B = 16 rows x 64B)
    int srow = wid * 16 + (lane >> 2);
    int sq8 = (lane & 3) * 8;
    const u16* ga  = Ab + (size_t)(bm * 64 + srow) * Dd + sq8;
    const u16* gb0 = Bb + (size_t)(bn * 128 + srow) * Dd + sq8;
    const u16* gb1 = gb0 + (size_t)64 * Dd;
    u16* la  = &As[wid * 16][0];       // wave-uniform LDS bases
    u16* lb0 = &Bs[wid * 16][0];
    u16* lb1 = &Bs[64 + wid * 16][0];

    f32x4 acc[2][4];
    for (int m = 0; m < 2; ++m)
        for (int n = 0; n < 4; ++n) acc[m][n] = (f32x4){0.f, 0.f, 0.f, 0.f};

    int frow = lane & 15;
    int fk = (lane >> 4) * 8;

    for (int k0 = 0; k0 < Dd; k0 += 32) {
        __syncthreads();
        gl_lds16(ga + k0, la);
        gl_lds16(gb0 + k0, lb0);
        gl_lds16(gb1 + k0, lb1);
        __syncthreads();   // compiler drains vmcnt before s_barrier
        bf16x8 af[2], bf[4];
        for (int m = 0; m < 2; ++m) af[m] = *(const bf16x8*)&As[wr * 32 + m * 16 + frow][fk];
        for (int n = 0; n < 4; ++n) bf[n] = *(const bf16x8*)&Bs[wc * 64 + n * 16 + frow][fk];
        for (int m = 0; m < 2; ++m)
            for (int n = 0; n < 4; ++n)
                acc[m][n] = __builtin_amdgcn_mfma_f32_16x16x32_bf16(af[m], bf[n], acc[m][n], 0, 0, 0);
    }

    int crow0 = bm * 64 + wr * 32 + (lane >> 4) * 4;
    int ccol0 = bn * 128 + wc * 64 + (lane & 15);
    for (int m = 0; m < 2; ++m)
        for (int q = 0; q < 4; ++q) {
            int row = crow0 + m * 16 + q;
            for (int n = 0; n < 4; ++n) {
                float v = acc[m][n][q];
                size_t off = (size_t)row * GN + ccol0 + n * 16;
                if (GB) ((u16*)Gv)[off] = f2bf(v);
                else ((float*)Gv)[off] = v;
            }
        }
}

// ---------------- per-pair kernel (5-barrier, fused dot, no-max softmax) ----------------
template <bool GB>
__global__ __launch_bounds__(256) void pair_kernel(const void* __restrict__ Gv,
                                                   const float* __restrict__ SS,
                                                   const float* __restrict__ II,
                                                   const int* __restrict__ s_l,
                                                   float* __restrict__ scores,
                                                   float* __restrict__ dA,
                                                   float* __restrict__ dB) {
    int j = blockIdx.x, i = blockIdx.y;
    int t = threadIdx.x;
    __shared__ float g[Rr][Ww];       // 36x40
    __shared__ float SSs[Ww][Ww];     // 40x40
    __shared__ float IIs[Rr][Rr];     // 36x36
    __shared__ float aAT[Ww][Rr];     // [w][r] normalized attn_i2t
    __shared__ float aBT[Rr][Ww];     // [r][w] normalized attn_t2i
    __shared__ float invA[Ww], invB[Rr];
    __shared__ float dotA[Rr], dotB[Ww];
    __shared__ float qpA[9][4][12];
    __shared__ float qpB[10][4][12];
    __shared__ float red[2];

    int L = s_l[j];

    // ---- P0: loads ----
    if (GB) {
        const u16* Gh = (const u16*)Gv;
        for (int idx = t; idx < Rr * 20; idx += 256) {
            int r = idx / 20, c2 = (idx - (idx / 20) * 20) * 2;
            unsigned int u = *(const unsigned int*)(Gh + (size_t)(i * Rr + r) * GN + j * Ww + c2);
            g[r][c2] = __uint_as_float(u << 16);
            g[r][c2 + 1] = __uint_as_float(u & 0xFFFF0000u);
        }
    } else {
        const float* Gf = (const float*)Gv;
        for (int idx = t; idx < Rr * 10; idx += 256) {
            int r = idx / 10, c4 = (idx - (idx / 10) * 10) * 4;
            *(float4*)&g[r][c4] = *(const float4*)(Gf + (size_t)(i * Rr + r) * GN + j * Ww + c4);
        }
    }
    for (int idx = t; idx < Ww * 10; idx += 256) {
        int w = idx / 10, c4 = (idx - (idx / 10) * 10) * 4;
        *(float4*)&SSs[w][c4] = *(const float4*)(SS + (size_t)j * Ww * Ww + w * Ww + c4);
    }
    for (int idx = t; idx < Rr * 9; idx += 256) {
        int r = idx / 9, c4 = (idx - (idx / 9) * 9) * 4;
        *(float4*)&IIs[r][c4] = *(const float4*)(II + (size_t)i * Rr * Rr + r * Rr + c4);
    }
    __syncthreads();

    // ---- P1: norms (A: 160 lanes 4-way, B: 72 lanes 2-way) ----
    if (t < 160) {
        int w = t >> 2, q = t & 3;
        float sum = 0.f;
#pragma unroll
        for (int k = 0; k < 9; ++k) {
            float x = g[q * 9 + k][w];
            x = x < 0.f ? 0.1f * x : x;
            sum += x * x;
        }
        sum += __shfl_xor(sum, 1);
        sum += __shfl_xor(sum, 2);
        if (q == 0) invA[w] = 6.f / (sqrtf(sum) + EPSf);
    } else if (t < 232) {
        int u = t - 160;
        int r = u >> 1, h = u & 1;
        float sum = 0.f;
#pragma unroll
        for (int k = 0; k < 20; ++k) {
            float x = g[r][h * 20 + k];
            x = x < 0.f ? 0.1f * x : x;
            sum += x * x;
        }
        sum += __shfl_xor(sum, 1);
        if (!h) invB[r] = 9.f / (sqrtf(sum) + EPSf);
    }
    __syncthreads();

    // ---- P2: softmax (no-max: |arg|<=6/9 bounded) + fused dot ----
    if (t < 72) {
        int r = t >> 1, h = t & 1;
        float sum = 0.f, dot = 0.f;
        float ebuf[20];
#pragma unroll
        for (int k = 0; k < 20; ++k) {
            int w = h * 20 + k;
            float e = 0.f;
            if (w < L) {
                float gx = g[r][w];
                float x = gx < 0.f ? 0.1f * gx : gx;
                e = __expf(x * invA[w]);
                dot += e * gx;
            }
            ebuf[k] = e;
            sum += e;
        }
        float fsum = sum + __shfl_xor(sum, 1);
        float fdot = dot + __shfl_xor(dot, 1);
        float inv = 1.f / fsum;
#pragma unroll
        for (int k = 0; k < 20; ++k) aAT[h * 20 + k][r] = ebuf[k] * inv;
        if (!h) dotA[r] = fdot * inv;
    } else if (t >= 128 && t < 208) {
        int u = t - 128;
        int w = u >> 1, h = u & 1;
        float sum = 0.f, dot = 0.f;
        float ebuf[18];
#pragma unroll
        for (int k = 0; k < 18; ++k) {
            int r = h * 18 + k;
            float gx = g[r][w];
            float x = gx < 0.f ? 0.1f * gx : gx;
            float e = __expf(x * invB[r]);
            dot += e * gx;
            ebuf[k] = e;
            sum += e;
        }
        float fsum = sum + __shfl_xor(sum, 1);
        float fdot = dot + __shfl_xor(dot, 1);
        float inv = 1.f / fsum;
#pragma unroll
        for (int k = 0; k < 18; ++k) aBT[h * 18 + k][w] = ebuf[k] * inv;
        if (!h) dotB[w] = fdot * inv;
    }
    __syncthreads();

    // ---- P3: quadratic forms, 4x4 register tiles ----
    if (t < 90) {
        int rg = t / 10, wg = t - (t / 10) * 10;
        float a[4][4];
        for (int x = 0; x < 4; ++x)
            for (int y = 0; y < 4; ++y) a[x][y] = 0.f;
        for (int w = 0; w < Ww; ++w) {
            float4 av = *(const float4*)&aAT[w][rg * 4];
            float4 sv = *(const float4*)&SSs[w][wg * 4];
            float avf[4] = {av.x, av.y, av.z, av.w};
            float svf[4] = {sv.x, sv.y, sv.z, sv.w};
            for (int ri = 0; ri < 4; ++ri)
                for (int wj = 0; wj < 4; ++wj) a[ri][wj] += avf[ri] * svf[wj];
        }
        float qp[4] = {0.f, 0.f, 0.f, 0.f};
        for (int wj = 0; wj < 4; ++wj) {
            float4 av2 = *(const float4*)&aAT[wg * 4 + wj][rg * 4];
            float avf[4] = {av2.x, av2.y, av2.z, av2.w};
            for (int ri = 0; ri < 4; ++ri) qp[ri] += avf[ri] * a[ri][wj];
        }
        for (int ri = 0; ri < 4; ++ri) qpA[rg][ri][wg] = qp[ri];
    } else if (t >= 128 && t < 218) {
        int u = t - 128;
        int wg = u / 9, rg = u - (u / 9) * 9;
        float a[4][4];
        for (int x = 0; x < 4; ++x)
            for (int y = 0; y < 4; ++y) a[x][y] = 0.f;
        for (int r = 0; r < Rr; ++r) {
            float4 bv = *(const float4*)&aBT[r][wg * 4];
            float4 iv = *(const float4*)&IIs[r][rg * 4];
            float bvf[4] = {bv.x, bv.y, bv.z, bv.w};
            float ivf[4] = {iv.x, iv.y, iv.z, iv.w};
            for (int wi = 0; wi < 4; ++wi)
                for (int rj = 0; rj < 4; ++rj) a[wi][rj] += bvf[wi] * ivf[rj];
        }
        float qp[4] = {0.f, 0.f, 0.f, 0.f};
        for (int rj = 0; rj < 4; ++rj) {
            float4 bv2 = *(const float4*)&aBT[rg * 4 + rj][wg * 4];
            float bvf[4] = {bv2.x, bv2.y, bv2.z, bv2.w};
            for (int wi = 0; wi < 4; ++wi) qp[wi] += bvf[wi] * a[wi][rj];
        }
        for (int wi = 0; wi < 4; ++wi) qpB[wg][wi][rg] = qp[wi];
    }
    __syncthreads();

    // ---- P4: sims + LSE (waves 0,1) + diag sums (waves 2,3) ----
    if (t < 64) {
        float e = 0.f;
        if (t < Rr) {
            float q = 0.f;
            for (int wg = 0; wg < 10; ++wg) q += qpA[t >> 2][t & 3][wg];
            float s1 = dotA[t] / fmaxf(sqrtf(IIs[t][t]) * sqrtf(fmaxf(q, 0.f)), EPSf);
            e = __expf(6.f * s1);
        }
        for (int off = 32; off; off >>= 1) e += __shfl_down(e, off);
        if (t == 0) red[0] = __logf(e) * (1.f / 6.f);
    } else if (t < 128) {
        int x = t - 64;
        float e = 0.f;
        if (x < L) {
            float q = 0.f;
            for (int rg = 0; rg < 9; ++rg) q += qpB[x >> 2][x & 3][rg];
            float s2 = dotB[x] / fmaxf(sqrtf(SSs[x][x]) * sqrtf(fmaxf(q, 0.f)), EPSf);
            e = __expf(6.f * s2);
        }
        for (int off = 32; off; off >>= 1) e += __shfl_down(e, off);
        if (x == 0) red[1] = __logf(e) * (1.f / 6.f);
    } else if (i == j) {
        if (t < 128 + Ww) {
            int w = t - 128;
            float sum = 0.f;
            for (int r = 0; r < Rr; ++r) sum += aAT[w][r];
            dA[i * Ww + w] = sum * (1.f / (float)Rr);
        } else if (t >= 192 && t < 192 + Rr) {
            int r = t - 192;
            float sum = 0.f;
            for (int w = 0; w < L; ++w) sum += aBT[r][w];
            dB[i * Rr + r] = sum / (float)L;
        }
    }
    __syncthreads();
    if (t == 0) scores[i * Bn + j] = 0.5f * (red[0] + red[1]);
}

// ---------------- diagonal outputs ----------------
__global__ __launch_bounds__(256) void diag_out_kernel(const float* __restrict__ s,
                                                       const float* __restrict__ im,
                                                       const int* __restrict__ s_l,
                                                       const float* __restrict__ dA,
                                                       const float* __restrict__ dB,
                                                       float* __restrict__ out) {
    int i = blockIdx.x;
    int d = blockIdx.y * 256 + threadIdx.x;
    int t = threadIdx.x;
    int L = s_l[i];
    __shared__ float aw[Ww], br[Rr];
    if (t < Ww) aw[t] = dA[i * Ww + t];
    if (t >= 64 && t < 64 + Rr) br[t - 64] = dB[i * Rr + (t - 64)];
    __syncthreads();
    float acc1 = 0.f;
    for (int w = 0; w < L; ++w) acc1 += aw[w] * s[((size_t)i * Ww + w) * Dd + d];
    out[1 + (size_t)i * Dd + d] = acc1;
    float acc2 = 0.f;
    for (int r = 0; r < Rr; ++r) acc2 += br[r] * im[((size_t)i * Rr + r) * Dd + d];
    out[1 + (size_t)Bn * Dd + (size_t)i * Dd + d] = acc2;
}

// ---------------- hinge loss ----------------
__global__ void loss_kernel(const float* __restrict__ scores, float* __restrict__ out) {
    int t = threadIdx.x;
    __shared__ float sc[Bn][Bn + 1];
    for (int idx = t; idx < Bn * Bn; idx += 64) sc[idx >> 6][idx & 63] = scores[idx];
    __syncthreads();
    float dt = sc[t][t];
    float rowmax = 0.f, colmax = 0.f;
    for (int k = 0; k < Bn; ++k) {
        if (k != t) {
            float cs = 0.2f + sc[t][k] - dt;
            if (cs > rowmax) rowmax = cs;
            float ci = 0.2f + sc[k][t] - dt;
            if (ci > colmax) colmax = ci;
        }
    }
    float v = rowmax + colmax;
    for (int off = 32; off; off >>= 1) v += __shfl_down(v, off);
    if (t == 0) out[0] = v;
}

extern "C" void kernel_launch(void* const* d_in, const int* in_sizes, int n_in,
                              void* d_out, int out_size, void* d_ws, size_t ws_size,
                              hipStream_t stream) {
    const float* im = (const float*)d_in[0];
    const float* s = (const float*)d_in[1];
    const int* s_l = (const int*)d_in[2];
    float* out = (float*)d_out;

    const size_t nAb = (size_t)GM * Dd;
    const size_t nBb = (size_t)GN * Dd;
    u16* Ab = (u16*)d_ws;
    u16* Bb = Ab + nAb;
    float* SS = (float*)(Bb + nBb);
    float* II = SS + (size_t)Bn * Ww * Ww;
    float* scores = II + (size_t)Bn * Rr * Rr;
    float* dA = scores + Bn * Bn;
    float* dB = dA + Bn * Ww;
    void* G = (void*)(dB + Bn * Rr);
    size_t base_bytes = (char*)G - (char*)d_ws;
    bool g_fp32 = (ws_size >= base_bytes + (size_t)GM * GN * 4);

    int nconv = (GM * Dd + GN * Dd) / 4;
    convert_kernel<<<(nconv + 255) / 256, 256, 0, stream>>>(im, s, s_l, Ab, Bb);
    gram_mfma_kernel<<<2 * Bn, 64, 0, stream>>>(Ab, Bb, SS, II);

    dim3 ggrid(GN / 128, GM / 64);
    dim3 pgrid(Bn, Bn);
    if (g_fp32) {
        gemm_mfma_kernel<false><<<ggrid, 256, 0, stream>>>(Ab, Bb, G);
        pair_kernel<false><<<pgrid, 256, 0, stream>>>(G, SS, II, s_l, scores, dA, dB);
    } else {
        gemm_mfma_kernel<true><<<ggrid, 256, 0, stream>>>(Ab, Bb, G);
        pair_kernel<true><<<pgrid, 256, 0, stream>>>(G, SS, II, s_l, scores, dA, dB);
    }

    dim3 dgrid(Bn, 4);
    diag_out_kernel<<<dgrid, 256, 0, stream>>>(s, im, s_l, dA, dB, out);
    loss_kernel<<<1, 64, 0, stream>>>(scores, out);
}

// Round 5
// 91.882 us; speedup vs baseline: 5.2188x; 1.2983x over previous
//
#include <hip/hip_runtime.h>
#include <math.h>

#define Bn 64
#define Rr 36
#define Ww 40
#define Dd 1024
#define GM 2304   // Bn*Rr
#define GN 2560   // Bn*Ww
#define EPSf 1e-8f

typedef unsigned short u16;
typedef __attribute__((ext_vector_type(8))) short bf16x8;
typedef __attribute__((ext_vector_type(4))) float f32x4;

struct alignas(8) U16x4 { u16 x, y, z, w; };

__device__ inline u16 f2bf(float x) {
    unsigned int u = __float_as_uint(x);
    u += 0x7FFFu + ((u >> 16) & 1u);
    return (u16)(u >> 16);
}

__device__ __forceinline__ void gl_lds16(const u16* g, u16* l) {
    __builtin_amdgcn_global_load_lds(
        (const __attribute__((address_space(1))) void*)g,
        (__attribute__((address_space(3))) void*)l, 16, 0, 0);
}

// ---------------- fp32 -> bf16 conversion (mask s rows) ----------------
__global__ __launch_bounds__(256) void convert_kernel(const float* __restrict__ im,
                                                      const float* __restrict__ s,
                                                      const int* __restrict__ s_l,
                                                      u16* __restrict__ Ab,
                                                      u16* __restrict__ Bb) {
    const int nA4 = GM * Dd / 4;
    const int nB4 = GN * Dd / 4;
    int idx = blockIdx.x * 256 + threadIdx.x;
    if (idx < nA4) {
        float4 v = *(const float4*)(im + (size_t)idx * 4);
        U16x4 o = {f2bf(v.x), f2bf(v.y), f2bf(v.z), f2bf(v.w)};
        *(U16x4*)(Ab + (size_t)idx * 4) = o;
    } else if (idx < nA4 + nB4) {
        int i2 = idx - nA4;
        int f = i2 * 4;
        int row = f >> 10;
        int j = row / Ww, w = row - j * Ww;
        U16x4 o = {0, 0, 0, 0};
        if (w < s_l[j]) {
            float4 v = *(const float4*)(s + (size_t)f);
            o.x = f2bf(v.x); o.y = f2bf(v.y); o.z = f2bf(v.z); o.w = f2bf(v.w);
        }
        *(U16x4*)(Bb + (size_t)i2 * 4) = o;
    }
}

// ---------------- Grams via single-wave MFMA ----------------
__global__ __launch_bounds__(64) void gram_mfma_kernel(const u16* __restrict__ Ab,
                                                       const u16* __restrict__ Bb,
                                                       float* __restrict__ SS,
                                                       float* __restrict__ II) {
    int b = blockIdx.x;
    bool isS = b < Bn;
    int idx = isS ? b : b - Bn;
    int n = isS ? Ww : Rr;
    const u16* base = isS ? (Bb + (size_t)idx * Ww * Dd) : (Ab + (size_t)idx * Rr * Dd);
    float* outp = isS ? (SS + (size_t)idx * Ww * Ww) : (II + (size_t)idx * Rr * Rr);
    int lane = threadIdx.x;
    int frow = lane & 15;
    int fk = (lane >> 4) * 8;

    f32x4 acc[3][3];
    for (int m = 0; m < 3; ++m)
        for (int p = 0; p < 3; ++p) acc[m][p] = (f32x4){0.f, 0.f, 0.f, 0.f};

    for (int k0 = 0; k0 < Dd; k0 += 32) {
        bf16x8 f[3];
        for (int m = 0; m < 3; ++m)
            f[m] = *(const bf16x8*)(base + (size_t)(m * 16 + frow) * Dd + k0 + fk);
        for (int m = 0; m < 3; ++m)
            for (int p = 0; p < 3; ++p)
                acc[m][p] = __builtin_amdgcn_mfma_f32_16x16x32_bf16(f[m], f[p], acc[m][p], 0, 0, 0);
    }
    int crow = (lane >> 4) * 4;
    int ccol = lane & 15;
    for (int m = 0; m < 3; ++m)
        for (int p = 0; p < 3; ++p)
            for (int q = 0; q < 4; ++q) {
                int row = m * 16 + crow + q;
                int col = p * 16 + ccol;
                if (row < n && col < n) outp[row * n + col] = acc[m][p][q];
            }
}

// ---------------- MFMA bf16 GEMM: BK=64, both-sides XOR swizzle ----------------
// 64x128 tile, 256 threads = 4 waves (2x2), wave tile 32x64, grid (20,36)=720
template <bool GB>
__global__ __launch_bounds__(256) void gemm_mfma_kernel(const u16* __restrict__ Ab,
                                                        const u16* __restrict__ Bb,
                                                        void* __restrict__ Gv) {
    __shared__ __align__(16) u16 As[64][64];    // 8 KB
    __shared__ __align__(16) u16 Bs[128][64];   // 16 KB
    int bn = blockIdx.x;
    int bm = blockIdx.y;
    int t = threadIdx.x;
    int lane = t & 63, wid = t >> 6;
    int wr = wid >> 1, wc = wid & 1;

    // staging: each instr = 8 rows x 128B; lane l -> row (l>>3), slot (l&7)
    // pre-swizzled global source: srcslot = (l&7) ^ (row&7); LDS dest linear
    int lrow8 = lane >> 3;                      // 0..7
    int sslot = (lane & 7) ^ lrow8;             // row&7 == lrow8 (8-row groups)
    const u16* ga  = Ab + ((size_t)(bm * 64 + wid * 16) + lrow8) * Dd + sslot * 8;
    const u16* gb  = Bb + ((size_t)(bn * 128 + wid * 32) + lrow8) * Dd + sslot * 8;
    u16* la0 = &As[wid * 16][0];
    u16* la1 = &As[wid * 16 + 8][0];
    u16* lb0 = &Bs[wid * 32][0];
    u16* lb1 = &Bs[wid * 32 + 8][0];
    u16* lb2 = &Bs[wid * 32 + 16][0];
    u16* lb3 = &Bs[wid * 32 + 24][0];

    f32x4 acc[2][4];
    for (int m = 0; m < 2; ++m)
        for (int n = 0; n < 4; ++n) acc[m][n] = (f32x4){0.f, 0.f, 0.f, 0.f};

    int frow = lane & 15;
    int cgr = lane >> 4;   // 0..3, k-subgroup within 32-slice

    for (int k0 = 0; k0 < Dd; k0 += 64) {
        __syncthreads();
        gl_lds16(ga + k0, la0);
        gl_lds16(ga + (size_t)8 * Dd + k0, la1);
        gl_lds16(gb + k0, lb0);
        gl_lds16(gb + (size_t)8 * Dd + k0, lb1);
        gl_lds16(gb + (size_t)16 * Dd + k0, lb2);
        gl_lds16(gb + (size_t)24 * Dd + k0, lb3);
        __syncthreads();   // drains vmcnt

        bf16x8 af[2][2], bf[4][2];
#pragma unroll
        for (int m = 0; m < 2; ++m) {
            int row = wr * 32 + m * 16 + frow;
#pragma unroll
            for (int ks = 0; ks < 2; ++ks) {
                int slot = (ks * 4 + cgr) ^ (row & 7);
                af[m][ks] = *(const bf16x8*)&As[row][slot * 8];
            }
        }
#pragma unroll
        for (int n = 0; n < 4; ++n) {
            int row = wc * 64 + n * 16 + frow;
#pragma unroll
            for (int ks = 0; ks < 2; ++ks) {
                int slot = (ks * 4 + cgr) ^ (row & 7);
                bf[n][ks] = *(const bf16x8*)&Bs[row][slot * 8];
            }
        }
#pragma unroll
        for (int ks = 0; ks < 2; ++ks)
#pragma unroll
            for (int m = 0; m < 2; ++m)
#pragma unroll
                for (int n = 0; n < 4; ++n)
                    acc[m][n] = __builtin_amdgcn_mfma_f32_16x16x32_bf16(af[m][ks], bf[n][ks], acc[m][n], 0, 0, 0);
    }

    int crow0 = bm * 64 + wr * 32 + (lane >> 4) * 4;
    int ccol0 = bn * 128 + wc * 64 + (lane & 15);
    for (int m = 0; m < 2; ++m)
        for (int q = 0; q < 4; ++q) {
            int row = crow0 + m * 16 + q;
            for (int n = 0; n < 4; ++n) {
                float v = acc[m][n][q];
                size_t off = (size_t)row * GN + ccol0 + n * 16;
                if (GB) ((u16*)Gv)[off] = f2bf(v);
                else ((float*)Gv)[off] = v;
            }
        }
}

// ---------------- per-(pair,path) single-wave kernel: NO barriers ----------------
// grid (Bn, Bn, 2), 64 threads. path 0 = i2t (A), path 1 = t2i (B).
template <bool GB>
__global__ __launch_bounds__(64) void pair_kernel(const void* __restrict__ Gv,
                                                  const float* __restrict__ SS,
                                                  const float* __restrict__ II,
                                                  const int* __restrict__ s_l,
                                                  float* __restrict__ score1,
                                                  float* __restrict__ score2,
                                                  float* __restrict__ dAp,
                                                  float* __restrict__ dBp) {
    int j = blockIdx.x, i = blockIdx.y, path = blockIdx.z;
    int t = threadIdx.x;
    __shared__ __align__(16) float gl[Rr * Ww];    // [r][w] 36x40
    __shared__ __align__(16) float att[1600];      // A: [w][36]; B: [r][40]
    __shared__ __align__(16) float invv[40];
    __shared__ __align__(16) float qp[360];        // A: [r][10]; B: [w][9]

    int L = s_l[j];

    // ---- load G row r=t into regs + LDS ----
    float grow[40];
    if (t < Rr) {
        if (GB) {
            const u16* gp = (const u16*)Gv + (size_t)(i * Rr + t) * GN + j * Ww;
#pragma unroll
            for (int q2 = 0; q2 < 20; ++q2) {
                unsigned int u = *(const unsigned int*)(gp + q2 * 2);
                grow[q2 * 2] = __uint_as_float(u << 16);
                grow[q2 * 2 + 1] = __uint_as_float(u & 0xFFFF0000u);
            }
        } else {
            const float* gp = (const float*)Gv + (size_t)(i * Rr + t) * GN + j * Ww;
#pragma unroll
            for (int q4 = 0; q4 < 10; ++q4) {
                float4 v = *(const float4*)(gp + q4 * 4);
                grow[q4 * 4] = v.x; grow[q4 * 4 + 1] = v.y;
                grow[q4 * 4 + 2] = v.z; grow[q4 * 4 + 3] = v.w;
            }
        }
#pragma unroll
        for (int q4 = 0; q4 < 10; ++q4) {
            float4 v = {grow[q4 * 4], grow[q4 * 4 + 1], grow[q4 * 4 + 2], grow[q4 * 4 + 3]};
            *(float4*)&gl[t * Ww + q4 * 4] = v;
        }
    }

    if (path == 0) {
        // ================= i2t path =================
        float iid = 0.f;
        if (t < Rr) iid = II[(size_t)i * Rr * Rr + t * Rr + t];

        // norm over regions r, per word w (lane = w)
        if (t < Ww) {
            float sum = 0.f;
            for (int r = 0; r < Rr; ++r) {
                float x = gl[r * Ww + t];
                x = x < 0.f ? 0.1f * x : x;
                sum += x * x;
            }
            invv[t] = 6.f / (sqrtf(sum) + EPSf);
        }

        // softmax over words + fused dot, per region r (lane = r), from regs
        float dot = 0.f;
        if (t < Rr) {
            float ebuf[40];
            float ssum = 0.f;
#pragma unroll
            for (int w = 0; w < Ww; ++w) {
                float e = 0.f;
                if (w < L) {
                    float gx = grow[w];
                    float x = gx < 0.f ? 0.1f * gx : gx;
                    e = __expf(x * invv[w]);
                    dot += e * gx;
                }
                ebuf[w] = e;
                ssum += e;
            }
            float inv = 1.f / ssum;
            dot *= inv;
#pragma unroll
            for (int w = 0; w < Ww; ++w) att[w * Rr + t] = ebuf[w] * inv;
        }

        // quadratic form q[r] = a_r^T SS a_r, 4x4 register tiles, 90 jobs / 2 rounds
#pragma unroll
        for (int rd = 0; rd < 2; ++rd) {
            int job = t + rd * 64;
            if (job < 90) {
                int rg = job / 10, wg = job - (job / 10) * 10;
                float a4[4][4];
#pragma unroll
                for (int x = 0; x < 4; ++x)
#pragma unroll
                    for (int y = 0; y < 4; ++y) a4[x][y] = 0.f;
                const float* SSp = SS + (size_t)j * Ww * Ww + wg * 4;
#pragma unroll 4
                for (int w = 0; w < Ww; ++w) {
                    float4 av = *(const float4*)&att[w * Rr + rg * 4];
                    float4 sv = *(const float4*)(SSp + w * Ww);
                    float avf[4] = {av.x, av.y, av.z, av.w};
                    float svf[4] = {sv.x, sv.y, sv.z, sv.w};
#pragma unroll
                    for (int ri = 0; ri < 4; ++ri)
#pragma unroll
                        for (int wj = 0; wj < 4; ++wj) a4[ri][wj] += avf[ri] * svf[wj];
                }
                float qv[4] = {0.f, 0.f, 0.f, 0.f};
#pragma unroll
                for (int wj = 0; wj < 4; ++wj) {
                    float4 av2 = *(const float4*)&att[(wg * 4 + wj) * Rr + rg * 4];
                    qv[0] += av2.x * a4[0][wj];
                    qv[1] += av2.y * a4[1][wj];
                    qv[2] += av2.z * a4[2][wj];
                    qv[3] += av2.w * a4[3][wj];
                }
#pragma unroll
                for (int ri = 0; ri < 4; ++ri) qp[(rg * 4 + ri) * 10 + wg] = qv[ri];
            }
        }

        // sims + LSE
        float e = 0.f;
        if (t < Rr) {
            float q = 0.f;
#pragma unroll
            for (int wg = 0; wg < 10; ++wg) q += qp[t * 10 + wg];
            float s1 = dot / fmaxf(sqrtf(iid) * sqrtf(fmaxf(q, 0.f)), EPSf);
            e = __expf(6.f * s1);
        }
#pragma unroll
        for (int off = 1; off < 64; off <<= 1) e += __shfl_xor(e, off);
        if (t == 0) score1[i * Bn + j] = __logf(e) * (1.f / 6.f);

        if (i == j && t < Ww) {
            float sum = 0.f;
#pragma unroll
            for (int rq = 0; rq < 9; ++rq) {
                float4 v = *(const float4*)&att[t * Rr + rq * 4];
                sum += v.x + v.y + v.z + v.w;
            }
            dAp[i * Ww + t] = sum * (1.f / (float)Rr);
        }
    } else {
        // ================= t2i path =================
        float ssd = 0.f;
        if (t < Ww) ssd = SS[(size_t)j * Ww * Ww + t * Ww + t];

        // norm over words w, per region r (lane = r), from regs
        if (t < Rr) {
            float sum = 0.f;
#pragma unroll
            for (int w = 0; w < Ww; ++w) {
                float x = grow[w];
                x = x < 0.f ? 0.1f * x : x;
                sum += x * x;
            }
            invv[t] = 9.f / (sqrtf(sum) + EPSf);
        }

        // softmax over regions + fused dot, per word w (lane = w)
        float dot = 0.f;
        if (t < Ww) {
            float ebuf[36];
            float ssum = 0.f;
#pragma unroll
            for (int r = 0; r < Rr; ++r) {
                float gx = gl[r * Ww + t];
                float x = gx < 0.f ? 0.1f * gx : gx;
                float e = __expf(x * invv[r]);
                dot += e * gx;
                ebuf[r] = e;
                ssum += e;
            }
            float inv = 1.f / ssum;
            dot *= inv;
#pragma unroll
            for (int r = 0; r < Rr; ++r) att[r * Ww + t] = ebuf[r] * inv;
        }

        // quadratic form q[w] = b_w^T II b_w, 90 jobs / 2 rounds
#pragma unroll
        for (int rd = 0; rd < 2; ++rd) {
            int job = t + rd * 64;
            if (job < 90) {
                int wg = job / 9, rg = job - (job / 9) * 9;
                float a4[4][4];
#pragma unroll
                for (int x = 0; x < 4; ++x)
#pragma unroll
                    for (int y = 0; y < 4; ++y) a4[x][y] = 0.f;
                const float* IIp = II + (size_t)i * Rr * Rr + rg * 4;
#pragma unroll 4
                for (int r = 0; r < Rr; ++r) {
                    float4 bv = *(const float4*)&att[r * Ww + wg * 4];
                    float4 iv = *(const float4*)(IIp + r * Rr);
                    float bvf[4] = {bv.x, bv.y, bv.z, bv.w};
                    float ivf[4] = {iv.x, iv.y, iv.z, iv.w};
#pragma unroll
                    for (int wi = 0; wi < 4; ++wi)
#pragma unroll
                        for (int rj = 0; rj < 4; ++rj) a4[wi][rj] += bvf[wi] * ivf[rj];
                }
                float qv[4] = {0.f, 0.f, 0.f, 0.f};
#pragma unroll
                for (int rj = 0; rj < 4; ++rj) {
                    float4 bv2 = *(const float4*)&att[(rg * 4 + rj) * Ww + wg * 4];
                    qv[0] += bv2.x * a4[0][rj];
                    qv[1] += bv2.y * a4[1][rj];
                    qv[2] += bv2.z * a4[2][rj];
                    qv[3] += bv2.w * a4[3][rj];
                }
#pragma unroll
                for (int wi = 0; wi < 4; ++wi) qp[(wg * 4 + wi) * 9 + rg] = qv[wi];
            }
        }

        // sims + masked LSE
        float e = 0.f;
        if (t < Ww) {
            float q = 0.f;
#pragma unroll
            for (int rg = 0; rg < 9; ++rg) q += qp[t * 9 + rg];
            float s2 = dot / fmaxf(sqrtf(ssd) * sqrtf(fmaxf(q, 0.f)), EPSf);
            e = (t < L) ? __expf(6.f * s2) : 0.f;
        }
#pragma unroll
        for (int off = 1; off < 64; off <<= 1) e += __shfl_xor(e, off);
        if (t == 0) score2[i * Bn + j] = __logf(e) * (1.f / 6.f);

        if (i == j && t < Rr) {
            float sum = 0.f;
#pragma unroll
            for (int w = 0; w < Ww; ++w) {
                float v = att[t * Ww + w];
                sum += (w < L) ? v : 0.f;
            }
            dBp[i * Rr + t] = sum / (float)L;
        }
    }
}

// ---------------- diagonal outputs ----------------
__global__ __launch_bounds__(256) void diag_out_kernel(const float* __restrict__ s,
                                                       const float* __restrict__ im,
                                                       const int* __restrict__ s_l,
                                                       const float* __restrict__ dA,
                                                       const float* __restrict__ dB,
                                                       float* __restrict__ out) {
    int i = blockIdx.x;
    int d = blockIdx.y * 256 + threadIdx.x;
    int t = threadIdx.x;
    int L = s_l[i];
    __shared__ float aw[Ww], br[Rr];
    if (t < Ww) aw[t] = dA[i * Ww + t];
    if (t >= 64 && t < 64 + Rr) br[t - 64] = dB[i * Rr + (t - 64)];
    __syncthreads();
    float acc1 = 0.f;
    for (int w = 0; w < L; ++w) acc1 += aw[w] * s[((size_t)i * Ww + w) * Dd + d];
    out[1 + (size_t)i * Dd + d] = acc1;
    float acc2 = 0.f;
    for (int r = 0; r < Rr; ++r) acc2 += br[r] * im[((size_t)i * Rr + r) * Dd + d];
    out[1 + (size_t)Bn * Dd + (size_t)i * Dd + d] = acc2;
}

// ---------------- hinge loss ----------------
__global__ void loss_kernel(const float* __restrict__ s1,
                            const float* __restrict__ s2,
                            float* __restrict__ out) {
    int t = threadIdx.x;
    __shared__ float sc[Bn][Bn + 1];
    for (int idx = t; idx < Bn * Bn; idx += 64)
        sc[idx >> 6][idx & 63] = 0.5f * (s1[idx] + s2[idx]);
    __syncthreads();
    float dt = sc[t][t];
    float rowmax = 0.f, colmax = 0.f;
    for (int k = 0; k < Bn; ++k) {
        if (k != t) {
            float cs = 0.2f + sc[t][k] - dt;
            if (cs > rowmax) rowmax = cs;
            float ci = 0.2f + sc[k][t] - dt;
            if (ci > colmax) colmax = ci;
        }
    }
    float v = rowmax + colmax;
    for (int off = 32; off; off >>= 1) v += __shfl_down(v, off);
    if (t == 0) out[0] = v;
}

extern "C" void kernel_launch(void* const* d_in, const int* in_sizes, int n_in,
                              void* d_out, int out_size, void* d_ws, size_t ws_size,
                              hipStream_t stream) {
    const float* im = (const float*)d_in[0];
    const float* s = (const float*)d_in[1];
    const int* s_l = (const int*)d_in[2];
    float* out = (float*)d_out;

    const size_t nAb = (size_t)GM * Dd;
    const size_t nBb = (size_t)GN * Dd;
    u16* Ab = (u16*)d_ws;
    u16* Bb = Ab + nAb;
    float* SS = (float*)(Bb + nBb);
    float* II = SS + (size_t)Bn * Ww * Ww;
    float* score1 = II + (size_t)Bn * Rr * Rr;
    float* score2 = score1 + Bn * Bn;
    float* dA = score2 + Bn * Bn;
    float* dB = dA + Bn * Ww;
    void* G = (void*)(dB + Bn * Rr);
    size_t base_bytes = (char*)G - (char*)d_ws;
    bool g_fp32 = (ws_size >= base_bytes + (size_t)GM * GN * 4);

    int nconv = (GM * Dd + GN * Dd) / 4;
    convert_kernel<<<(nconv + 255) / 256, 256, 0, stream>>>(im, s, s_l, Ab, Bb);
    gram_mfma_kernel<<<2 * Bn, 64, 0, stream>>>(Ab, Bb, SS, II);

    dim3 ggrid(GN / 128, GM / 64);
    dim3 pgrid(Bn, Bn, 2);
    if (g_fp32) {
        gemm_mfma_kernel<false><<<ggrid, 256, 0, stream>>>(Ab, Bb, G);
        pair_kernel<false><<<pgrid, 64, 0, stream>>>(G, SS, II, s_l, score1, score2, dA, dB);
    } else {
        gemm_mfma_kernel<true><<<ggrid, 256, 0, stream>>>(Ab, Bb, G);
        pair_kernel<true><<<pgrid, 64, 0, stream>>>(G, SS, II, s_l, score1, score2, dA, dB);
    }

    dim3 dgrid(Bn, 4);
    diag_out_kernel<<<dgrid, 256, 0, stream>>>(s, im, s_l, dA, dB, out);
    loss_kernel<<<1, 64, 0, stream>>>(score1, score2, out);
}

// Round 6
// 79.371 us; speedup vs baseline: 6.0414x; 1.1576x over previous
//
#include <hip/hip_runtime.h>
#include <math.h>

#define Bn 64
#define Rr 36
#define Ww 40
#define Dd 1024
#define GM 2304   // Bn*Rr
#define GN 2560   // Bn*Ww
#define GLP 44    // glb row pitch in u16 (bank-conflict-free padding)
#define EPSf 1e-8f

typedef unsigned short u16;
typedef __attribute__((ext_vector_type(8))) short bf16x8;
typedef __attribute__((ext_vector_type(4))) float f32x4;

struct alignas(8) U16x4 { u16 x, y, z, w; };

__device__ inline u16 f2bf(float x) {
    unsigned int u = __float_as_uint(x);
    u += 0x7FFFu + ((u >> 16) & 1u);
    return (u16)(u >> 16);
}
__device__ inline float bf2f(u16 h) {
    return __uint_as_float(((unsigned int)h) << 16);
}

__device__ __forceinline__ void gl_lds16(const u16* g, u16* l) {
    __builtin_amdgcn_global_load_lds(
        (const __attribute__((address_space(1))) void*)g,
        (__attribute__((address_space(3))) void*)l, 16, 0, 0);
}

// ---------------- fp32 -> bf16 conversion (mask s rows) ----------------
__global__ __launch_bounds__(256) void convert_kernel(const float* __restrict__ im,
                                                      const float* __restrict__ s,
                                                      const int* __restrict__ s_l,
                                                      u16* __restrict__ Ab,
                                                      u16* __restrict__ Bb) {
    const int nA4 = GM * Dd / 4;
    const int nB4 = GN * Dd / 4;
    int idx = blockIdx.x * 256 + threadIdx.x;
    if (idx < nA4) {
        float4 v = *(const float4*)(im + (size_t)idx * 4);
        U16x4 o = {f2bf(v.x), f2bf(v.y), f2bf(v.z), f2bf(v.w)};
        *(U16x4*)(Ab + (size_t)idx * 4) = o;
    } else if (idx < nA4 + nB4) {
        int i2 = idx - nA4;
        int f = i2 * 4;
        int row = f >> 10;
        int j = row / Ww, w = row - j * Ww;
        U16x4 o = {0, 0, 0, 0};
        if (w < s_l[j]) {
            float4 v = *(const float4*)(s + (size_t)f);
            o.x = f2bf(v.x); o.y = f2bf(v.y); o.z = f2bf(v.z); o.w = f2bf(v.w);
        }
        *(U16x4*)(Bb + (size_t)i2 * 4) = o;
    }
}

// ---------------- Grams via MFMA, 4-wave K-split ----------------
__global__ __launch_bounds__(256) void gram_mfma_kernel(const u16* __restrict__ Ab,
                                                        const u16* __restrict__ Bb,
                                                        float* __restrict__ SS,
                                                        float* __restrict__ II) {
    int b = blockIdx.x;
    bool isS = b < Bn;
    int idx = isS ? b : b - Bn;
    int n = isS ? Ww : Rr;
    const u16* base = isS ? (Bb + (size_t)idx * Ww * Dd) : (Ab + (size_t)idx * Rr * Dd);
    float* outp = isS ? (SS + (size_t)idx * Ww * Ww) : (II + (size_t)idx * Rr * Rr);
    int t = threadIdx.x, lane = t & 63, wid = t >> 6;
    int frow = lane & 15, fk = (lane >> 4) * 8;
    __shared__ float red[3][64][37];

    f32x4 acc[3][3];
    for (int m = 0; m < 3; ++m)
        for (int p = 0; p < 3; ++p) acc[m][p] = (f32x4){0.f, 0.f, 0.f, 0.f};

    for (int ks = 0; ks < 8; ++ks) {
        int k0 = wid * 256 + ks * 32;
        bf16x8 f[3];
        for (int m = 0; m < 3; ++m)
            f[m] = *(const bf16x8*)(base + (size_t)(m * 16 + frow) * Dd + k0 + fk);
        for (int m = 0; m < 3; ++m)
            for (int p = 0; p < 3; ++p)
                acc[m][p] = __builtin_amdgcn_mfma_f32_16x16x32_bf16(f[m], f[p], acc[m][p], 0, 0, 0);
    }
    if (wid) {
        for (int m = 0; m < 3; ++m)
            for (int p = 0; p < 3; ++p)
                for (int q = 0; q < 4; ++q)
                    red[wid - 1][lane][(m * 3 + p) * 4 + q] = acc[m][p][q];
    }
    __syncthreads();
    if (wid == 0) {
        for (int wv = 0; wv < 3; ++wv)
            for (int m = 0; m < 3; ++m)
                for (int p = 0; p < 3; ++p)
                    for (int q = 0; q < 4; ++q)
                        acc[m][p][q] += red[wv][lane][(m * 3 + p) * 4 + q];
        int crow = (lane >> 4) * 4, ccol = lane & 15;
        for (int m = 0; m < 3; ++m)
            for (int p = 0; p < 3; ++p)
                for (int q = 0; q < 4; ++q) {
                    int row = m * 16 + crow + q;
                    int col = p * 16 + ccol;
                    if (row < n && col < n) outp[row * n + col] = acc[m][p][q];
                }
    }
}

// ---------------- MFMA bf16 GEMM: BK=64, XOR swizzle, double-buffered ----------------
template <bool GB>
__global__ __launch_bounds__(256) void gemm_mfma_kernel(const u16* __restrict__ Ab,
                                                        const u16* __restrict__ Bb,
                                                        void* __restrict__ Gv) {
    __shared__ __align__(16) u16 As[2][64][64];    // 16 KB
    __shared__ __align__(16) u16 Bs[2][128][64];   // 32 KB
    int bn = blockIdx.x;
    int bm = blockIdx.y;
    int t = threadIdx.x;
    int lane = t & 63, wid = t >> 6;
    int wr = wid >> 1, wc = wid & 1;

    int lrow8 = lane >> 3;
    int sslot = (lane & 7) ^ lrow8;   // pre-swizzled global source, linear LDS dest
    const u16* ga = Ab + ((size_t)(bm * 64 + wid * 16) + lrow8) * Dd + sslot * 8;
    const u16* gb = Bb + ((size_t)(bn * 128 + wid * 32) + lrow8) * Dd + sslot * 8;

    f32x4 acc[2][4];
    for (int m = 0; m < 2; ++m)
        for (int n = 0; n < 4; ++n) acc[m][n] = (f32x4){0.f, 0.f, 0.f, 0.f};

    int frow = lane & 15;
    int cgr = lane >> 4;

#define STAGE(BI, KK) do { \
        gl_lds16(ga + (KK), &As[BI][wid * 16][0]); \
        gl_lds16(ga + (size_t)8 * Dd + (KK), &As[BI][wid * 16 + 8][0]); \
        gl_lds16(gb + (KK), &Bs[BI][wid * 32][0]); \
        gl_lds16(gb + (size_t)8 * Dd + (KK), &Bs[BI][wid * 32 + 8][0]); \
        gl_lds16(gb + (size_t)16 * Dd + (KK), &Bs[BI][wid * 32 + 16][0]); \
        gl_lds16(gb + (size_t)24 * Dd + (KK), &Bs[BI][wid * 32 + 24][0]); \
    } while (0)

    STAGE(0, 0);
    for (int step = 0; step < 16; ++step) {
        int cur = step & 1;
        __syncthreads();                     // drains vmcnt: buf[cur] ready, buf[cur^1] free
        if (step < 15) STAGE(cur ^ 1, (step + 1) * 64);   // overlap with compute below
        bf16x8 af[2][2], bf[4][2];
#pragma unroll
        for (int m = 0; m < 2; ++m) {
            int row = wr * 32 + m * 16 + frow;
#pragma unroll
            for (int ks = 0; ks < 2; ++ks) {
                int slot = (ks * 4 + cgr) ^ (row & 7);
                af[m][ks] = *(const bf16x8*)&As[cur][row][slot * 8];
            }
        }
#pragma unroll
        for (int n = 0; n < 4; ++n) {
            int row = wc * 64 + n * 16 + frow;
#pragma unroll
            for (int ks = 0; ks < 2; ++ks) {
                int slot = (ks * 4 + cgr) ^ (row & 7);
                bf[n][ks] = *(const bf16x8*)&Bs[cur][row][slot * 8];
            }
        }
#pragma unroll
        for (int ks = 0; ks < 2; ++ks)
#pragma unroll
            for (int m = 0; m < 2; ++m)
#pragma unroll
                for (int n = 0; n < 4; ++n)
                    acc[m][n] = __builtin_amdgcn_mfma_f32_16x16x32_bf16(af[m][ks], bf[n][ks], acc[m][n], 0, 0, 0);
    }
#undef STAGE

    int crow0 = bm * 64 + wr * 32 + (lane >> 4) * 4;
    int ccol0 = bn * 128 + wc * 64 + (lane & 15);
    for (int m = 0; m < 2; ++m)
        for (int q = 0; q < 4; ++q) {
            int row = crow0 + m * 16 + q;
            for (int n = 0; n < 4; ++n) {
                float v = acc[m][n][q];
                size_t off = (size_t)row * GN + ccol0 + n * 16;
                if (GB) ((u16*)Gv)[off] = f2bf(v);
                else ((float*)Gv)[off] = v;
            }
        }
}

// ---------------- per-pair kernel: 2 waves (i2t | t2i), 2 barriers ----------------
template <bool GB>
__global__ __launch_bounds__(128) void pair_kernel(const void* __restrict__ Gv,
                                                   const float* __restrict__ SS,
                                                   const float* __restrict__ II,
                                                   const int* __restrict__ s_l,
                                                   float* __restrict__ score1,
                                                   float* __restrict__ score2,
                                                   float* __restrict__ dAp,
                                                   float* __restrict__ dBp) {
    int j = blockIdx.x, i = blockIdx.y;
    int t = threadIdx.x, lane = t & 63, wid = t >> 6;
    __shared__ __align__(16) u16 glb[Rr * GLP];     // g bf16, pitch 44
    __shared__ __align__(16) u16 attA[Ww * Rr];     // [w][r] unnormalized e
    __shared__ __align__(16) u16 attB[Rr * Ww];     // [r][w] unnormalized e
    __shared__ float invA[Ww], invB[Rr], sA[Rr], sB[Ww];
    __shared__ float qpA[360], qpB[360];
    int L = s_l[j];
    float iid = 0.f, ssd = 0.f;

    // ---------- phase 0: wave0 loads G tile + invB; wave1 preloads SS diag ----------
    if (wid == 0) {
        if (lane < Rr) {
            iid = II[(size_t)i * Rr * Rr + lane * (Rr + 1)];
            if (GB) {
                const u16* gp = (const u16*)Gv + (size_t)(i * Rr + lane) * GN + j * Ww;
#pragma unroll
                for (int q = 0; q < 10; ++q)
                    *(uint2*)&glb[lane * GLP + q * 4] = *(const uint2*)(gp + q * 4);
            } else {
                const float* gp = (const float*)Gv + (size_t)(i * Rr + lane) * GN + j * Ww;
#pragma unroll
                for (int q = 0; q < 10; ++q) {
                    float4 v = *(const float4*)(gp + q * 4);
                    U16x4 h = {f2bf(v.x), f2bf(v.y), f2bf(v.z), f2bf(v.w)};
                    *(uint2*)&glb[lane * GLP + q * 4] = *(const uint2*)&h;
                }
            }
            float sum = 0.f;
#pragma unroll 8
            for (int w = 0; w < Ww; ++w) {
                float x = bf2f(glb[lane * GLP + w]);
                x = x < 0.f ? 0.1f * x : x;
                sum += x * x;
            }
            invB[lane] = 9.f / (sqrtf(sum) + EPSf);
        }
    } else {
        if (lane < Ww) ssd = SS[(size_t)j * Ww * Ww + lane * (Ww + 1)];
    }
    __syncthreads();
    // ---------- phase 1: wave1 computes invA (column norms) ----------
    if (wid == 1 && lane < Ww) {
        float sum = 0.f;
#pragma unroll 6
        for (int r = 0; r < Rr; ++r) {
            float x = bf2f(glb[r * GLP + lane]);
            x = x < 0.f ? 0.1f * x : x;
            sum += x * x;
        }
        invA[lane] = 6.f / (sqrtf(sum) + EPSf);
    }
    __syncthreads();
    // ---------- phase 2: independent per-wave paths ----------
    if (wid == 0) {
        // ===== i2t =====
        float dot = 0.f, myinv = 0.f;
        if (lane < Rr) {
            float ssum = 0.f;
#pragma unroll 8
            for (int w = 0; w < Ww; ++w) {
                float e = 0.f;
                if (w < L) {
                    float gx = bf2f(glb[lane * GLP + w]);
                    float x = gx < 0.f ? 0.1f * gx : gx;
                    e = __expf(x * invA[w]);
                    dot += e * gx;
                }
                attA[w * Rr + lane] = f2bf(e);
                ssum += e;
            }
            myinv = 1.f / ssum;
            dot *= myinv;
            sA[lane] = myinv;
        }
        // quadratic forms: job = wg*9+rg so 9-lane groups share the SS strip (L2 dedup)
#pragma unroll
        for (int rd = 0; rd < 2; ++rd) {
            int job = lane + rd * 64;
            if (job < 90) {
                int wg = job / 9, rg = job - (job / 9) * 9;
                float a4[4][4];
#pragma unroll
                for (int x = 0; x < 4; ++x)
#pragma unroll
                    for (int y = 0; y < 4; ++y) a4[x][y] = 0.f;
                const float* SSp = SS + (size_t)j * Ww * Ww + wg * 4;
#pragma unroll 4
                for (int w = 0; w < Ww; ++w) {
                    ushort4 a16 = *(const ushort4*)&attA[w * Rr + rg * 4];
                    float4 sv = *(const float4*)(SSp + w * Ww);
                    float av0 = bf2f(a16.x), av1 = bf2f(a16.y), av2 = bf2f(a16.z), av3 = bf2f(a16.w);
                    a4[0][0] += av0 * sv.x; a4[0][1] += av0 * sv.y; a4[0][2] += av0 * sv.z; a4[0][3] += av0 * sv.w;
                    a4[1][0] += av1 * sv.x; a4[1][1] += av1 * sv.y; a4[1][2] += av1 * sv.z; a4[1][3] += av1 * sv.w;
                    a4[2][0] += av2 * sv.x; a4[2][1] += av2 * sv.y; a4[2][2] += av2 * sv.z; a4[2][3] += av2 * sv.w;
                    a4[3][0] += av3 * sv.x; a4[3][1] += av3 * sv.y; a4[3][2] += av3 * sv.z; a4[3][3] += av3 * sv.w;
                }
                float qv0 = 0.f, qv1 = 0.f, qv2 = 0.f, qv3 = 0.f;
#pragma unroll
                for (int wj = 0; wj < 4; ++wj) {
                    ushort4 b16 = *(const ushort4*)&attA[(wg * 4 + wj) * Rr + rg * 4];
                    qv0 += bf2f(b16.x) * a4[0][wj];
                    qv1 += bf2f(b16.y) * a4[1][wj];
                    qv2 += bf2f(b16.z) * a4[2][wj];
                    qv3 += bf2f(b16.w) * a4[3][wj];
                }
                qpA[(rg * 4 + 0) * 10 + wg] = qv0;
                qpA[(rg * 4 + 1) * 10 + wg] = qv1;
                qpA[(rg * 4 + 2) * 10 + wg] = qv2;
                qpA[(rg * 4 + 3) * 10 + wg] = qv3;
            }
        }
        // sims + LSE
        float e1 = 0.f;
        if (lane < Rr) {
            float q = 0.f;
#pragma unroll
            for (int wg = 0; wg < 10; ++wg) q += qpA[lane * 10 + wg];
            q *= myinv * myinv;
            float s1 = dot / fmaxf(sqrtf(iid) * sqrtf(fmaxf(q, 0.f)), EPSf);
            e1 = __expf(6.f * s1);
        }
#pragma unroll
        for (int off = 1; off < 64; off <<= 1) e1 += __shfl_xor(e1, off);
        if (lane == 0) score1[i * Bn + j] = __logf(e1) * (1.f / 6.f);
        if (i == j && lane < Ww) {
            float sum = 0.f;
#pragma unroll 6
            for (int r = 0; r < Rr; ++r) sum += bf2f(attA[lane * Rr + r]) * sA[r];
            dAp[i * Ww + lane] = sum * (1.f / (float)Rr);
        }
    } else {
        // ===== t2i =====
        float dot = 0.f, myinv = 0.f;
        if (lane < Ww) {
            float ssum = 0.f;
#pragma unroll 6
            for (int r = 0; r < Rr; ++r) {
                float gx = bf2f(glb[r * GLP + lane]);
                float x = gx < 0.f ? 0.1f * gx : gx;
                float e = __expf(x * invB[r]);
                dot += e * gx;
                attB[r * Ww + lane] = f2bf(e);
                ssum += e;
            }
            myinv = 1.f / ssum;
            dot *= myinv;
            sB[lane] = myinv;
        }
        // quadratic forms: job = rg*10+wg so 10-lane groups share the II strip
#pragma unroll
        for (int rd = 0; rd < 2; ++rd) {
            int job = lane + rd * 64;
            if (job < 90) {
                int rg = job / 10, wg = job - (job / 10) * 10;
                float a4[4][4];
#pragma unroll
                for (int x = 0; x < 4; ++x)
#pragma unroll
                    for (int y = 0; y < 4; ++y) a4[x][y] = 0.f;
                const float* IIp = II + (size_t)i * Rr * Rr + rg * 4;
#pragma unroll 4
                for (int r = 0; r < Rr; ++r) {
                    ushort4 b16 = *(const ushort4*)&attB[r * Ww + wg * 4];
                    float4 iv = *(const float4*)(IIp + r * Rr);
                    float bv0 = bf2f(b16.x), bv1 = bf2f(b16.y), bv2 = bf2f(b16.z), bv3 = bf2f(b16.w);
                    a4[0][0] += bv0 * iv.x; a4[0][1] += bv0 * iv.y; a4[0][2] += bv0 * iv.z; a4[0][3] += bv0 * iv.w;
                    a4[1][0] += bv1 * iv.x; a4[1][1] += bv1 * iv.y; a4[1][2] += bv1 * iv.z; a4[1][3] += bv1 * iv.w;
                    a4[2][0] += bv2 * iv.x; a4[2][1] += bv2 * iv.y; a4[2][2] += bv2 * iv.z; a4[2][3] += bv2 * iv.w;
                    a4[3][0] += bv3 * iv.x; a4[3][1] += bv3 * iv.y; a4[3][2] += bv3 * iv.z; a4[3][3] += bv3 * iv.w;
                }
                float qv0 = 0.f, qv1 = 0.f, qv2 = 0.f, qv3 = 0.f;
#pragma unroll
                for (int rj = 0; rj < 4; ++rj) {
                    ushort4 b2 = *(const ushort4*)&attB[(rg * 4 + rj) * Ww + wg * 4];
                    qv0 += bf2f(b2.x) * a4[0][rj];
                    qv1 += bf2f(b2.y) * a4[1][rj];
                    qv2 += bf2f(b2.z) * a4[2][rj];
                    qv3 += bf2f(b2.w) * a4[3][rj];
                }
                qpB[(wg * 4 + 0) * 9 + rg] = qv0;
                qpB[(wg * 4 + 1) * 9 + rg] = qv1;
                qpB[(wg * 4 + 2) * 9 + rg] = qv2;
                qpB[(wg * 4 + 3) * 9 + rg] = qv3;
            }
        }
        float e2 = 0.f;
        if (lane < Ww) {
            float q = 0.f;
#pragma unroll
            for (int rg = 0; rg < 9; ++rg) q += qpB[lane * 9 + rg];
            q *= myinv * myinv;
            float s2 = dot / fmaxf(sqrtf(ssd) * sqrtf(fmaxf(q, 0.f)), EPSf);
            e2 = (lane < L) ? __expf(6.f * s2) : 0.f;
        }
#pragma unroll
        for (int off = 1; off < 64; off <<= 1) e2 += __shfl_xor(e2, off);
        if (lane == 0) score2[i * Bn + j] = __logf(e2) * (1.f / 6.f);
        if (i == j && lane < Rr) {
            float sum = 0.f;
            for (int w = 0; w < L; ++w) sum += bf2f(attB[lane * Ww + w]) * sB[w];
            dBp[i * Rr + lane] = sum / (float)L;
        }
    }
}

// ---------------- diagonal outputs + fused hinge loss ----------------
__global__ __launch_bounds__(256) void diag_out_kernel(const u16* __restrict__ Ab,
                                                       const u16* __restrict__ Bb,
                                                       const int* __restrict__ s_l,
                                                       const float* __restrict__ dA,
                                                       const float* __restrict__ dB,
                                                       const float* __restrict__ score1,
                                                       const float* __restrict__ score2,
                                                       float* __restrict__ out) {
    int t = threadIdx.x;
    if (blockIdx.y == 4) {
        if (blockIdx.x != 0) return;
        __shared__ float sc[Bn][Bn + 1];
        for (int idx = t; idx < Bn * Bn; idx += 256)
            sc[idx >> 6][idx & 63] = 0.5f * (score1[idx] + score2[idx]);
        __syncthreads();
        if (t < 64) {
            float dt = sc[t][t];
            float rowmax = 0.f, colmax = 0.f;
            for (int k = 0; k < Bn; ++k) {
                if (k != t) {
                    rowmax = fmaxf(rowmax, 0.2f + sc[t][k] - dt);
                    colmax = fmaxf(colmax, 0.2f + sc[k][t] - dt);
                }
            }
            float v = rowmax + colmax;
            for (int off = 32; off; off >>= 1) v += __shfl_down(v, off);
            if (t == 0) out[0] = v;
        }
        return;
    }
    int i = blockIdx.x;
    int d = blockIdx.y * 256 + t;
    int L = s_l[i];
    __shared__ float aw[Ww], br[Rr];
    if (t < Ww) aw[t] = dA[i * Ww + t];
    if (t >= 64 && t < 64 + Rr) br[t - 64] = dB[i * Rr + (t - 64)];
    __syncthreads();
    float acc1 = 0.f;
    for (int w = 0; w < L; ++w) acc1 += aw[w] * bf2f(Bb[((size_t)i * Ww + w) * Dd + d]);
    out[1 + (size_t)i * Dd + d] = acc1;
    float acc2 = 0.f;
    for (int r = 0; r < Rr; ++r) acc2 += br[r] * bf2f(Ab[((size_t)i * Rr + r) * Dd + d]);
    out[1 + (size_t)Bn * Dd + (size_t)i * Dd + d] = acc2;
}

extern "C" void kernel_launch(void* const* d_in, const int* in_sizes, int n_in,
                              void* d_out, int out_size, void* d_ws, size_t ws_size,
                              hipStream_t stream) {
    const float* im = (const float*)d_in[0];
    const float* s = (const float*)d_in[1];
    const int* s_l = (const int*)d_in[2];
    float* out = (float*)d_out;

    const size_t nAb = (size_t)GM * Dd;
    const size_t nBb = (size_t)GN * Dd;
    u16* Ab = (u16*)d_ws;
    u16* Bb = Ab + nAb;
    float* SS = (float*)(Bb + nBb);
    float* II = SS + (size_t)Bn * Ww * Ww;
    float* score1 = II + (size_t)Bn * Rr * Rr;
    float* score2 = score1 + Bn * Bn;
    float* dA = score2 + Bn * Bn;
    float* dB = dA + Bn * Ww;
    void* G = (void*)(dB + Bn * Rr);
    size_t base_bytes = (char*)G - (char*)d_ws;
    bool g_fp32 = (ws_size >= base_bytes + (size_t)GM * GN * 4);

    int nconv = (GM * Dd + GN * Dd) / 4;
    convert_kernel<<<(nconv + 255) / 256, 256, 0, stream>>>(im, s, s_l, Ab, Bb);
    gram_mfma_kernel<<<2 * Bn, 256, 0, stream>>>(Ab, Bb, SS, II);

    dim3 ggrid(GN / 128, GM / 64);
    dim3 pgrid(Bn, Bn);
    if (g_fp32) {
        gemm_mfma_kernel<false><<<ggrid, 256, 0, stream>>>(Ab, Bb, G);
        pair_kernel<false><<<pgrid, 128, 0, stream>>>(G, SS, II, s_l, score1, score2, dA, dB);
    } else {
        gemm_mfma_kernel<true><<<ggrid, 256, 0, stream>>>(Ab, Bb, G);
        pair_kernel<true><<<pgrid, 128, 0, stream>>>(G, SS, II, s_l, score1, score2, dA, dB);
    }

    dim3 dgrid(Bn, 5);
    diag_out_kernel<<<dgrid, 256, 0, stream>>>(Ab, Bb, s_l, dA, dB, score1, score2, out);
}